// Round 3
// baseline (9909.254 us; speedup 1.0000x reference)
//
#include <hip/hip_runtime.h>

#define NN 8192
#define NE 131072
#define KNN 20
#define CH 4096   // gram chunk rows
#define GBM 128
#define GBN 128
#define GBK 64

typedef __attribute__((ext_vector_type(4))) float f32x4;
typedef __attribute__((ext_vector_type(8))) __bf16 bf16x8;

// ---------------- utility ----------------
__global__ void k_zero(float* p, int n){
  int i = blockIdx.x*256 + threadIdx.x;
  if (i < n) p[i] = 0.f;
}
__global__ void k_zero_i(int* p, int n){
  int i = blockIdx.x*256 + threadIdx.x;
  if (i < n) p[i] = 0;
}

__device__ __forceinline__ unsigned short f2bf(float x){
  unsigned u = __float_as_uint(x);
  unsigned r = (u + 0x7fff + ((u >> 16) & 1)) >> 16;
  return (unsigned short)r;
}
__device__ __forceinline__ float bf2f(unsigned short h){
  return __uint_as_float((unsigned)h << 16);
}
__device__ __forceinline__ void gload16(const void* g, void* l){
  __builtin_amdgcn_global_load_lds(
      (const __attribute__((address_space(1))) void*)g,
      (__attribute__((address_space(3))) void*)l, 16, 0, 0);
}

// ---------------- graph prep ----------------
__global__ void k_count(const int* __restrict__ src, const int* __restrict__ dst,
                        int* cs, int* cd){
  int e = blockIdx.x*256 + threadIdx.x;
  if (e < NE){ atomicAdd(&cs[src[e]], 1); atomicAdd(&cd[dst[e]], 1); }
}
__global__ void k_deg(const int* cs, const int* cd, float* dout, float* din){
  int i = blockIdx.x*256 + threadIdx.x;
  if (i < NN){
    dout[i] = rsqrtf((float)max(cs[i], 1));
    din[i]  = rsqrtf((float)max(cd[i], 1));
  }
}
__global__ void k_scan(const int* __restrict__ cnt, int* __restrict__ off){
  __shared__ int sh[256];
  __shared__ int carry;
  int tid = threadIdx.x;
  if (tid == 0) carry = 0;
  __syncthreads();
  for (int base = 0; base < NN; base += 256){
    int v = cnt[base + tid];
    int x = v;
    sh[tid] = x; __syncthreads();
    for (int o = 1; o < 256; o <<= 1){
      int y = (tid >= o) ? sh[tid - o] : 0;
      __syncthreads();
      x += y; sh[tid] = x;
      __syncthreads();
    }
    off[base + tid] = carry + x - v;
    __syncthreads();
    if (tid == 255){
      carry += x;
      if (base + 256 == NN) off[NN] = carry;
    }
    __syncthreads();
  }
}
__global__ void k_fill(const int* __restrict__ src, const int* __restrict__ dst,
                       const int* __restrict__ roff, int* cursor, int* csr){
  int e = blockIdx.x*256 + threadIdx.x;
  if (e < NE){
    int d = dst[e];
    int p = atomicAdd(&cursor[d], 1);
    csr[roff[d] + p] = src[e];
  }
}

// ---------------- gconv1 fused (3 -> 256) ----------------
__global__ void k_gconv1(const float* __restrict__ feat, const int* __restrict__ roff,
                         const int* __restrict__ csr, const float* __restrict__ dout,
                         const float* __restrict__ din, const float* __restrict__ Wc1,
                         const float* __restrict__ bc1, float* __restrict__ h1){
  int wid = threadIdx.x >> 6, lane = threadIdx.x & 63;
  int i = blockIdx.x*4 + wid;
  float a0=0.f, a1=0.f, a2=0.f;
  int beg = roff[i], end = roff[i+1];
  for (int t = beg + lane; t < end; t += 64){
    int s = csr[t]; float w = dout[s];
    a0 += feat[s*3+0]*w; a1 += feat[s*3+1]*w; a2 += feat[s*3+2]*w;
  }
  for (int m = 32; m; m >>= 1){
    a0 += __shfl_xor(a0, m); a1 += __shfl_xor(a1, m); a2 += __shfl_xor(a2, m);
  }
  float dn = din[i];
  a0 *= dn; a1 *= dn; a2 *= dn;
  for (int c = lane; c < 256; c += 64){
    float r = a0*Wc1[c] + a1*Wc1[256+c] + a2*Wc1[512+c] + bc1[c];
    h1[(size_t)i*256 + c] = fmaxf(r, 0.f);
  }
}

// ---------------- row squared norms (C=256) ----------------
__global__ void k_sq(const float* __restrict__ X, float* __restrict__ sq){
  int wid = threadIdx.x >> 6, lane = threadIdx.x & 63;
  int i = blockIdx.x*4 + wid;
  float4 v = *(const float4*)&X[(size_t)i*256 + lane*4];
  float s = v.x*v.x + v.y*v.y + v.z*v.z + v.w*v.w;
  for (int m = 32; m; m >>= 1) s += __shfl_xor(s, m);
  if (lane == 0) sq[i] = s;
}

// ---------------- split f32 -> [hi|lo] bf16, Xcat[n][512] ----------------
__global__ void k_split(const float* __restrict__ X, unsigned short* __restrict__ xcat){
  int row = blockIdx.x, c = threadIdx.x;
  float x = X[(size_t)row*256 + c];
  unsigned short h = f2bf(x);
  unsigned short lo = f2bf(x - bf2f(h));
  xcat[(size_t)row*512 + c] = h;
  xcat[(size_t)row*512 + 256 + c] = lo;
}

// ---------------- MFMA gram: G[chunk row][j] = x_i . x_j (split bf16, K=768) ----------------
// A sections: {hi, lo, hi}; B sections: {hi, hi, lo}
__global__ __launch_bounds__(256)
void k_gram_mfma(const unsigned short* __restrict__ Xcat,
                 float* __restrict__ G, int r0){
  __shared__ unsigned short sA[GBM*GBK];  // 16 KB, swizzled granules
  __shared__ unsigned short sB[GBN*GBK];
  int tid = threadIdx.x;
  int lw = tid >> 6, l = tid & 63;
  int rbl = blockIdx.y*GBM;      // local chunk row base
  int rb = r0 + rbl;             // global source row base (A)
  int cb = blockIdx.x*GBN;       // global source row base (B) = G column base

  int srow = l >> 3;             // 0..7
  int scol = (l & 7) ^ srow;     // swizzled source granule (row&7 == srow)
  const unsigned short* srcA[4];
  const unsigned short* srcB[4];
  char* dstA[4]; char* dstB[4];
  #pragma unroll
  for (int i = 0; i < 4; i++){
    int c = lw*4 + i;
    int row = c*8 + srow;
    srcA[i] = Xcat + (size_t)(rb + row)*512 + scol*8;
    srcB[i] = Xcat + (size_t)(cb + row)*512 + scol*8;
    dstA[i] = (char*)sA + c*1024;
    dstB[i] = (char*)sB + c*1024;
  }

  int wm = lw >> 1, wn = lw & 1;
  int fm = l & 15, kg = l >> 4;
  unsigned offA[4][2], offB[4][2];
  #pragma unroll
  for (int mf = 0; mf < 4; mf++){
    int rowa = wm*64 + mf*16 + fm;
    int rowb = wn*64 + mf*16 + fm;
    #pragma unroll
    for (int ks = 0; ks < 2; ks++){
      offA[mf][ks] = rowa*128 + (((unsigned)(ks*4 + kg) ^ (rowa & 7)))*16;
      offB[mf][ks] = rowb*128 + (((unsigned)(ks*4 + kg) ^ (rowb & 7)))*16;
    }
  }

  f32x4 acc[4][4];
  #pragma unroll
  for (int m = 0; m < 4; m++)
    #pragma unroll
    for (int n = 0; n < 4; n++) acc[m][n] = (f32x4){0.f,0.f,0.f,0.f};

  #pragma unroll
  for (int s = 0; s < 12; s++){
    int sec = s >> 2;
    int inner = (s & 3)*64;
    int cbA = (sec == 1 ? 256 : 0) + inner;
    int cbB = (sec == 2 ? 256 : 0) + inner;
    #pragma unroll
    for (int i = 0; i < 4; i++){
      gload16(srcA[i] + cbA, dstA[i]);
      gload16(srcB[i] + cbB, dstB[i]);
    }
    __syncthreads();
    #pragma unroll
    for (int ks = 0; ks < 2; ks++){
      bf16x8 a[4], b[4];
      #pragma unroll
      for (int mf = 0; mf < 4; mf++) a[mf] = *(const bf16x8*)((const char*)sA + offA[mf][ks]);
      #pragma unroll
      for (int nf = 0; nf < 4; nf++) b[nf] = *(const bf16x8*)((const char*)sB + offB[nf][ks]);
      #pragma unroll
      for (int mf = 0; mf < 4; mf++)
        #pragma unroll
        for (int nf = 0; nf < 4; nf++)
          acc[mf][nf] = __builtin_amdgcn_mfma_f32_16x16x32_bf16(a[mf], b[nf], acc[mf][nf], 0, 0, 0);
    }
    __syncthreads();
  }

  #pragma unroll
  for (int mf = 0; mf < 4; mf++){
    int orow = rbl + wm*64 + mf*16 + kg*4;
    #pragma unroll
    for (int nf = 0; nf < 4; nf++){
      int ocol = cb + wn*64 + nf*16 + fm;
      #pragma unroll
      for (int r = 0; r < 4; r++)
        G[(size_t)(orow + r)*NN + ocol] = acc[mf][nf][r];
    }
  }
}

// ---------------- top-K per row: latency-batched scan + wave-threshold filter ----------------
// Exactness: T = min over lanes of kd[19] is an upper bound on the global 20th
// smallest (any lane's 20th >= global 20th). Any element of the final top-20 has
// key <= final 20th <= T at all times, so it always passes the filter; it can only
// be evicted from a lane list by 20 composite-smaller elements in that lane, which
// would already exclude it from the global top-20. In-lane strict-< insertion is
// stable (later-scanned equal values have larger idx); cross-lane merge uses the
// full (val,idx) composite compare.
__global__ __launch_bounds__(256)
void k_topk(const float* __restrict__ G, const float* __restrict__ sq,
            int r0, int* __restrict__ idxo){
  __shared__ float lsq[NN];   // 32 KB: sq staged once per block
  int tid = threadIdx.x;
  for (int t = tid; t < NN/4; t += 256)
    ((float4*)lsq)[t] = ((const float4*)sq)[t];
  __syncthreads();

  int wid = tid >> 6, lane = tid & 63;
  int rl = blockIdx.x*4 + wid;
  int gr = r0 + rl;
  const float4* row4 = (const float4*)(G + (size_t)rl*NN);
  float sqr = sq[gr];

  float kd[KNN]; int ki[KNN];
  #pragma unroll
  for (int u = 0; u < KNN; u++){ kd[u] = INFINITY; ki[u] = 0x7fffffff; }
  float T = INFINITY;

  float4 ra[4], rb[4];

#define LOADB(buf, o) { \
    _Pragma("unroll") \
    for (int q = 0; q < 4; q++) buf[q] = row4[lane + (o)*256 + q*64]; }

#define INS(kc, jc) { \
    if ((kc) <= T){ \
      float nk = (kc); int ni = (jc); \
      _Pragma("unroll") \
      for (int u = 0; u < KNN; u++){ \
        bool sw = nk < kd[u]; \
        float tv = kd[u]; int ti = ki[u]; \
        if (sw){ kd[u] = nk; ki[u] = ni; nk = tv; ni = ti; } \
      } \
    } }

#define PROC(buf, o) { \
    _Pragma("unroll") \
    for (int q = 0; q < 4; q++){ \
      float4 g = buf[q]; \
      int jb = 4*lane + ((o)*4 + q)*256; \
      float4 s = *(const float4*)&lsq[jb]; \
      float k0 = (sqr + s.x) - 2.f*g.x; \
      float k1 = (sqr + s.y) - 2.f*g.y; \
      float k2 = (sqr + s.z) - 2.f*g.z; \
      float k3 = (sqr + s.w) - 2.f*g.w; \
      float mn = fminf(fminf(k0,k1), fminf(k2,k3)); \
      if (__any(mn <= T)){ \
        INS(k0, jb+0); INS(k1, jb+1); INS(k2, jb+2); INS(k3, jb+3); \
        float tt = kd[KNN-1]; \
        _Pragma("unroll") \
        for (int mm = 32; mm; mm >>= 1) tt = fminf(tt, __shfl_xor(tt, mm)); \
        T = tt; \
      } \
    } }

  LOADB(ra, 0);
  #pragma unroll
  for (int oo = 0; oo < 4; oo++){
    int o0 = oo*2, o1 = oo*2 + 1;
    if (o0 < 7) LOADB(rb, o0+1);
    PROC(ra, o0);
    if (o1 < 7) LOADB(ra, o1+1);
    PROC(rb, o1);
  }
#undef LOADB
#undef INS
#undef PROC

  // cross-lane merge: 20 rounds of wave argmin on (val, idx)
  for (int r = 0; r < KNN; r++){
    float cv = kd[0]; int ci = ki[0]; int cl = lane;
    for (int m = 32; m; m >>= 1){
      float ov = __shfl_xor(cv, m); int oi = __shfl_xor(ci, m); int ol = __shfl_xor(cl, m);
      if (ov < cv || (ov == cv && oi < ci)){ cv = ov; ci = oi; cl = ol; }
    }
    if (lane == cl){
      #pragma unroll
      for (int u = 0; u < KNN-1; u++){ kd[u] = kd[u+1]; ki[u] = ki[u+1]; }
      kd[KNN-1] = INFINITY; ki[KNN-1] = 0x7fffffff;
    }
    if (lane == 0) idxo[(size_t)gr*KNN + r] = ci;
  }
}

// ---------------- Wd = Wtop - Wbot ----------------
__global__ void k_wd(const float* __restrict__ W, float* __restrict__ Wd, int rows, int M){
  int t = blockIdx.x*256 + threadIdx.x;
  if (t < rows*M) Wd[t] = W[t] - W[rows*M + t];
}

// ---------------- generic tiled matmul: C = A(nxK) @ B(KxM) [+bias][relu] ----------------
__global__ __launch_bounds__(256)
void k_mm(const float* __restrict__ A, const float* __restrict__ B,
          const float* __restrict__ bias, float* __restrict__ Cout,
          int n, int Kd, int M, int relu){
  __shared__ float la[16][68], lb[16][68];
  int tid = threadIdx.x;
  int rb = blockIdx.y*64, cb = blockIdx.x*64;
  int lr = tid >> 2, lq = (tid & 3)*4;
  int ty = tid >> 4, tx = tid & 15;
  float acc[4][4] = {};
  for (int k0 = 0; k0 < Kd; k0 += 16){
    __syncthreads();
    #pragma unroll
    for (int u = 0; u < 4; u++){
      int k = k0 + lq + u;
      la[lq+u][lr] = (k < Kd) ? A[(size_t)(rb+lr)*Kd + k] : 0.f;
    }
    int kk = tid >> 4; int cc = (tid & 15)*4;
    #pragma unroll
    for (int u = 0; u < 4; u++){
      int c = cb + cc + u; int k = k0 + kk;
      lb[kk][cc+u] = (k < Kd && c < M) ? B[(size_t)k*M + c] : 0.f;
    }
    __syncthreads();
    #pragma unroll
    for (int k = 0; k < 16; k++){
      float4 a = *(const float4*)&la[k][ty*4];
      float4 b = *(const float4*)&lb[k][tx*4];
      float avv[4] = {a.x,a.y,a.z,a.w}, bvv[4] = {b.x,b.y,b.z,b.w};
      #pragma unroll
      for (int u = 0; u < 4; u++)
        #pragma unroll
        for (int v = 0; v < 4; v++) acc[u][v] += avv[u]*bvv[v];
    }
  }
  #pragma unroll
  for (int u = 0; u < 4; u++){
    int r = rb + ty*4 + u;
    #pragma unroll
    for (int v = 0; v < 4; v++){
      int c = cb + tx*4 + v;
      if (c < M){
        float x = acc[u][v] + (bias ? bias[c] : 0.f);
        if (relu) x = fmaxf(x, 0.f);
        Cout[(size_t)r*M + c] = x;
      }
    }
  }
}

// ---------------- stats over A[i]+P[j] per channel ----------------
template<int C>
__global__ __launch_bounds__(256)
void k_stats1(const float* __restrict__ A, const float* __restrict__ P,
              const int* __restrict__ idx, float* __restrict__ ssum, float* __restrict__ ssq){
  __shared__ int si[128], sj[128];
  int tid = threadIdx.x;
  int s0 = blockIdx.x*128;
  if (tid < 128){ si[tid] = (s0 + tid)/KNN; sj[tid] = idx[s0 + tid]; }
  __syncthreads();
  constexpr int MPAR = 256/C;
  int tc = tid % C, sr = tid / C;
  float s = 0.f, q = 0.f;
  for (int m = sr; m < 128; m += MPAR){
    float v = A[(size_t)si[m]*C + tc] + P[(size_t)sj[m]*C + tc];
    s += v; q += v*v;
  }
  if constexpr (MPAR > 1){
    __shared__ float rs[256], rq[256];
    rs[tid] = s; rq[tid] = q; __syncthreads();
    if (sr == 0){
      for (int u = 1; u < MPAR; u++){ s += rs[u*C + tc]; q += rq[u*C + tc]; }
    }
  }
  if (sr == 0){ atomicAdd(&ssum[tc], s); atomicAdd(&ssq[tc], q); }
}

// ---------------- column stats over dense X (rows = N*KNN) ----------------
template<int C>
__global__ __launch_bounds__(256)
void k_colstats(const float* __restrict__ X, float* __restrict__ ssum, float* __restrict__ ssq){
  constexpr int MPAR = 256/C;
  int tid = threadIdx.x;
  int tc = tid % C, sr = tid / C;
  int base = blockIdx.x*256;
  float s = 0.f, q = 0.f;
  for (int m = sr; m < 256; m += MPAR){
    float v = X[(size_t)(base + m)*C + tc];
    s += v; q += v*v;
  }
  if constexpr (MPAR > 1){
    __shared__ float rs[256], rq[256];
    rs[tid] = s; rq[tid] = q; __syncthreads();
    if (sr == 0){
      for (int u = 1; u < MPAR; u++){ s += rs[u*C + tc]; q += rq[u*C + tc]; }
    }
  }
  if (sr == 0){ atomicAdd(&ssum[tc], s); atomicAdd(&ssq[tc], q); }
}

__global__ void k_bn_final(const float* __restrict__ ssum, const float* __restrict__ ssq,
                           const float* __restrict__ g, const float* __restrict__ be,
                           float* __restrict__ sb, float* __restrict__ tb, int C, float invn){
  int c = threadIdx.x;
  if (c < C){
    float mu = ssum[c]*invn;
    float var = fmaxf(ssq[c]*invn - mu*mu, 0.f);
    float s = g[c]*rsqrtf(var + 1e-5f);
    sb[c] = s; tb[c] = be[c] - mu*s;
  }
}

// ---------------- per-edge matmul: out = relu(bn1(A[i]+P[j])) @ W + bias ----------------
template<int C>
__global__ __launch_bounds__(256)
void k_edge_mm(const float* __restrict__ A, const float* __restrict__ P,
               const int* __restrict__ idx, const float* __restrict__ sb,
               const float* __restrict__ tb, const float* __restrict__ W,
               const float* __restrict__ bias, float* __restrict__ out){
  constexpr int BM   = (C == 256) ? 32 : 64;
  constexpr int KT   = (C == 256) ? 16 : 64;
  constexpr int COLG = C/8;
  constexpr int ROWG = 256/COLG;
  constexpr int EPT  = BM/ROWG;
  constexpr int MPAR = 256/C;
  __shared__ float e2[BM][C+1];
  __shared__ float wt[KT][C+4];
  __shared__ int sj[BM];
  int tid = threadIdx.x;
  int s0 = blockIdx.x*BM;
  if (tid < BM) sj[tid] = idx[s0 + tid];
  __syncthreads();
  for (int mb = 0; mb < BM; mb += MPAR){
    int m = mb + tid / C;
    int c = tid % C;
    int i = (s0 + m)/KNN;
    int j = sj[m];
    float v = (A[(size_t)i*C + c] + P[(size_t)j*C + c])*sb[c] + tb[c];
    e2[m][c] = fmaxf(v, 0.f);
  }
  float acc[EPT][8];
  #pragma unroll
  for (int m = 0; m < EPT; m++)
    #pragma unroll
    for (int u = 0; u < 8; u++) acc[m][u] = 0.f;
  int tr = tid / COLG, tc = tid % COLG;
  for (int kt = 0; kt < C; kt += KT){
    __syncthreads();
    for (int t = tid; t < KT*C; t += 256){
      wt[t / C][t % C] = W[(size_t)(kt + t/C)*C + (t % C)];
    }
    __syncthreads();
    #pragma unroll 4
    for (int k = 0; k < KT; k++){
      float4 w0 = *(const float4*)&wt[k][tc*8];
      float4 w1 = *(const float4*)&wt[k][tc*8 + 4];
      float b[8] = {w0.x,w0.y,w0.z,w0.w,w1.x,w1.y,w1.z,w1.w};
      #pragma unroll
      for (int m = 0; m < EPT; m++){
        float a = e2[tr*EPT + m][kt + k];
        #pragma unroll
        for (int u = 0; u < 8; u++) acc[m][u] += a*b[u];
      }
    }
  }
  #pragma unroll
  for (int m = 0; m < EPT; m++){
    int row = s0 + tr*EPT + m;
    float4 o0, o1;
    o0.x = acc[m][0] + bias[tc*8+0]; o0.y = acc[m][1] + bias[tc*8+1];
    o0.z = acc[m][2] + bias[tc*8+2]; o0.w = acc[m][3] + bias[tc*8+3];
    o1.x = acc[m][4] + bias[tc*8+4]; o1.y = acc[m][5] + bias[tc*8+5];
    o1.z = acc[m][6] + bias[tc*8+6]; o1.w = acc[m][7] + bias[tc*8+7];
    *(float4*)&out[(size_t)row*C + tc*8]     = o0;
    *(float4*)&out[(size_t)row*C + tc*8 + 4] = o1;
  }
}

// ---------------- bn2 + relu + max over K ----------------
template<int C>
__global__ void k_maxpool(const float* __restrict__ X, const float* __restrict__ sb,
                          const float* __restrict__ tb, float* __restrict__ H){
  constexpr int NPB = 256/C;
  int node = blockIdx.x*NPB + threadIdx.x / C;
  int c = threadIdx.x % C;
  float s = sb[c], t = tb[c];
  float mx = 0.f;
  for (int k = 0; k < KNN; k++){
    float v = X[(size_t)(node*KNN + k)*C + c]*s + t;
    mx = fmaxf(mx, v);
  }
  H[(size_t)node*C + c] = mx;
}

// ---------------- gconv aggregation ----------------
template<int C>
__global__ void k_agg(const float* __restrict__ X, const int* __restrict__ roff,
                      const int* __restrict__ csr, const float* __restrict__ dout,
                      const float* __restrict__ din, float* __restrict__ XA){
  int i = blockIdx.x; int c = threadIdx.x;
  float acc = 0.f;
  int b = roff[i], e = roff[i+1];
  for (int t = b; t < e; t++){
    int s = csr[t];
    acc += X[(size_t)s*C + c]*dout[s];
  }
  XA[(size_t)i*C + c] = acc*din[i];
}

// ================= host =================
extern "C" void kernel_launch(void* const* d_in, const int* in_sizes, int n_in,
                              void* d_out, int out_size, void* d_ws, size_t ws_size,
                              hipStream_t stream){
  const float* feat = (const float*)d_in[0];
  const int*   src  = (const int*)d_in[1];
  const int*   dst  = (const int*)d_in[2];
  const float* Wc1  = (const float*)d_in[3];
  const float* bc1  = (const float*)d_in[4];
  const float* Wc2  = (const float*)d_in[5];
  const float* bc2  = (const float*)d_in[6];
  const float* Wc3  = (const float*)d_in[7];
  const float* bc3  = (const float*)d_in[8];
  const float* W11  = (const float*)d_in[9];
  const float* b11  = (const float*)d_in[10];
  const float* g11  = (const float*)d_in[11];
  const float* be11 = (const float*)d_in[12];
  const float* W12  = (const float*)d_in[13];
  const float* b12  = (const float*)d_in[14];
  const float* g12  = (const float*)d_in[15];
  const float* be12 = (const float*)d_in[16];
  const float* W21  = (const float*)d_in[17];
  const float* b21  = (const float*)d_in[18];
  const float* g21  = (const float*)d_in[19];
  const float* be21 = (const float*)d_in[20];
  const float* W22  = (const float*)d_in[21];
  const float* b22  = (const float*)d_in[22];
  const float* g22  = (const float*)d_in[23];
  const float* be22 = (const float*)d_in[24];
  float* out = (float*)d_out;

  char* w = (char*)d_ws; size_t off = 0;
  auto alloc = [&](size_t bytes)->void*{
    void* p = w + off;
    off += bytes; off = (off + 255) & ~(size_t)255;
    return p;
  };
  int* cnt_s  = (int*)alloc(NN*4);
  int* cnt_d  = (int*)alloc(NN*4);
  int* roff   = (int*)alloc((NN+1)*4);
  int* cursor = (int*)alloc(NN*4);
  int* csr    = (int*)alloc(NE*4);
  int* idx    = (int*)alloc((size_t)NN*KNN*4);
  float* dout = (float*)alloc(NN*4);
  float* din  = (float*)alloc(NN*4);
  float* sqv  = (float*)alloc(NN*4);
  float* h1   = (float*)alloc((size_t)NN*256*4);
  float* h2   = (float*)alloc((size_t)NN*256*4);
  float* h3   = (float*)alloc((size_t)NN*256*4);
  float* h4   = (float*)alloc((size_t)NN*64*4);
  float* xa   = (float*)alloc((size_t)NN*256*4);
  float* Abuf = (float*)alloc((size_t)NN*256*4);
  float* Pbuf = (float*)alloc((size_t)NN*256*4);
  float* Wd   = (float*)alloc(256*256*4);
  float* ssum = (float*)alloc(256*4);
  float* ssq  = (float*)alloc(256*4);
  float* sbn  = (float*)alloc(256*4);
  float* tbn  = (float*)alloc(256*4);
  float* out2 = (float*)alloc((size_t)NN*KNN*256*4);   // 167.8 MB
  // kNN scratch aliases out2 (consumed before edge_mm writes out2):
  float* gram = out2;                                        // CH*NN*4 = 134.2 MB
  unsigned short* xcat = (unsigned short*)(out2 + (size_t)CH*NN);  // 8.4 MB
  (void)ws_size; (void)n_in; (void)in_sizes; (void)out_size;

  const float invn = 1.0f / (float)(NN*KNN);

  // graph prep
  k_zero_i<<<32, 256, 0, stream>>>(cnt_s, NN);
  k_zero_i<<<32, 256, 0, stream>>>(cnt_d, NN);
  k_zero_i<<<32, 256, 0, stream>>>(cursor, NN);
  k_count<<<NE/256, 256, 0, stream>>>(src, dst, cnt_s, cnt_d);
  k_deg<<<32, 256, 0, stream>>>(cnt_s, cnt_d, dout, din);
  k_scan<<<1, 256, 0, stream>>>(cnt_d, roff);
  k_fill<<<NE/256, 256, 0, stream>>>(src, dst, roff, cursor, csr);

  // gconv1 -> h1
  k_gconv1<<<NN/4, 256, 0, stream>>>(feat, roff, csr, dout, din, Wc1, bc1, h1);

  // ---- edge conv 1 (input h1, 256 -> 256 -> 256) ----
  k_sq<<<NN/4, 256, 0, stream>>>(h1, sqv);
  k_split<<<NN, 256, 0, stream>>>(h1, xcat);
  for (int r0 = 0; r0 < NN; r0 += CH){
    k_gram_mfma<<<dim3(NN/GBN, CH/GBM), 256, 0, stream>>>(xcat, gram, r0);
    k_topk<<<CH/4, 256, 0, stream>>>(gram, sqv, r0, idx);
  }
  k_wd<<<256, 256, 0, stream>>>(W11, Wd, 256, 256);
  k_mm<<<dim3(4, NN/64), 256, 0, stream>>>(h1, Wd, b11, Abuf, NN, 256, 256, 0);
  k_mm<<<dim3(4, NN/64), 256, 0, stream>>>(h1, W11 + 256*256, nullptr, Pbuf, NN, 256, 256, 0);
  k_zero<<<2, 256, 0, stream>>>(ssum, 256); k_zero<<<2, 256, 0, stream>>>(ssq, 256);
  k_stats1<256><<<NN*KNN/128, 256, 0, stream>>>(Abuf, Pbuf, idx, ssum, ssq);
  k_bn_final<<<1, 256, 0, stream>>>(ssum, ssq, g11, be11, sbn, tbn, 256, invn);
  k_edge_mm<256><<<NN*KNN/32, 256, 0, stream>>>(Abuf, Pbuf, idx, sbn, tbn, W12, b12, out2);
  k_zero<<<2, 256, 0, stream>>>(ssum, 256); k_zero<<<2, 256, 0, stream>>>(ssq, 256);
  k_colstats<256><<<NN*KNN/256, 256, 0, stream>>>(out2, ssum, ssq);
  k_bn_final<<<1, 256, 0, stream>>>(ssum, ssq, g12, be12, sbn, tbn, 256, invn);
  k_maxpool<256><<<NN, 256, 0, stream>>>(out2, sbn, tbn, h2);

  // gconv2 -> h3
  k_agg<256><<<NN, 256, 0, stream>>>(h2, roff, csr, dout, din, xa);
  k_mm<<<dim3(4, NN/64), 256, 0, stream>>>(xa, Wc2, bc2, h3, NN, 256, 256, 1);

  // ---- edge conv 2 (input h3, 256 -> 64 -> 64) ----
  k_sq<<<NN/4, 256, 0, stream>>>(h3, sqv);
  k_split<<<NN, 256, 0, stream>>>(h3, xcat);
  for (int r0 = 0; r0 < NN; r0 += CH){
    k_gram_mfma<<<dim3(NN/GBN, CH/GBM), 256, 0, stream>>>(xcat, gram, r0);
    k_topk<<<CH/4, 256, 0, stream>>>(gram, sqv, r0, idx);
  }
  k_wd<<<64, 256, 0, stream>>>(W21, Wd, 256, 64);
  k_mm<<<dim3(1, NN/64), 256, 0, stream>>>(h3, Wd, b21, Abuf, NN, 256, 64, 0);
  k_mm<<<dim3(1, NN/64), 256, 0, stream>>>(h3, W21 + 256*64, nullptr, Pbuf, NN, 256, 64, 0);
  k_zero<<<2, 256, 0, stream>>>(ssum, 256); k_zero<<<2, 256, 0, stream>>>(ssq, 256);
  k_stats1<64><<<NN*KNN/128, 256, 0, stream>>>(Abuf, Pbuf, idx, ssum, ssq);
  k_bn_final<<<1, 256, 0, stream>>>(ssum, ssq, g21, be21, sbn, tbn, 64, invn);
  k_edge_mm<64><<<NN*KNN/64, 256, 0, stream>>>(Abuf, Pbuf, idx, sbn, tbn, W22, b22, out2);
  k_zero<<<2, 256, 0, stream>>>(ssum, 256); k_zero<<<2, 256, 0, stream>>>(ssq, 256);
  k_colstats<64><<<NN*KNN/256, 256, 0, stream>>>(out2, ssum, ssq);
  k_bn_final<<<1, 256, 0, stream>>>(ssum, ssq, g22, be22, sbn, tbn, 64, invn);
  k_maxpool<64><<<NN/4, 256, 0, stream>>>(out2, sbn, tbn, h4);

  // gconv3 -> out
  k_agg<64><<<NN, 64, 0, stream>>>(h4, roff, csr, dout, din, xa);
  k_mm<<<dim3(1, NN/64), 256, 0, stream>>>(xa, Wc3, bc3, out, NN, 64, 32, 0);
}

// Round 4
// 5714.748 us; speedup vs baseline: 1.7340x; 1.7340x over previous
//
#include <hip/hip_runtime.h>

#define NN 8192
#define NE 131072
#define KNN 20
#define CH 4096   // gram chunk rows
#define GBM 128
#define GBN 128
#define GBK 64

typedef __attribute__((ext_vector_type(4))) float f32x4;
typedef __attribute__((ext_vector_type(8))) __bf16 bf16x8;

// ---------------- utility ----------------
__global__ void k_zero(float* p, int n){
  int i = blockIdx.x*256 + threadIdx.x;
  if (i < n) p[i] = 0.f;
}
__global__ void k_zero_i(int* p, int n){
  int i = blockIdx.x*256 + threadIdx.x;
  if (i < n) p[i] = 0;
}

__device__ __forceinline__ unsigned short f2bf(float x){
  unsigned u = __float_as_uint(x);
  unsigned r = (u + 0x7fff + ((u >> 16) & 1)) >> 16;
  return (unsigned short)r;
}
__device__ __forceinline__ float bf2f(unsigned short h){
  return __uint_as_float((unsigned)h << 16);
}
__device__ __forceinline__ void gload16(const void* g, void* l){
  __builtin_amdgcn_global_load_lds(
      (const __attribute__((address_space(1))) void*)g,
      (__attribute__((address_space(3))) void*)l, 16, 0, 0);
}

// ---------------- graph prep ----------------
__global__ void k_count(const int* __restrict__ src, const int* __restrict__ dst,
                        int* cs, int* cd){
  int e = blockIdx.x*256 + threadIdx.x;
  if (e < NE){ atomicAdd(&cs[src[e]], 1); atomicAdd(&cd[dst[e]], 1); }
}
__global__ void k_deg(const int* cs, const int* cd, float* dout, float* din){
  int i = blockIdx.x*256 + threadIdx.x;
  if (i < NN){
    dout[i] = rsqrtf((float)max(cs[i], 1));
    din[i]  = rsqrtf((float)max(cd[i], 1));
  }
}
__global__ void k_scan(const int* __restrict__ cnt, int* __restrict__ off){
  __shared__ int sh[256];
  __shared__ int carry;
  int tid = threadIdx.x;
  if (tid == 0) carry = 0;
  __syncthreads();
  for (int base = 0; base < NN; base += 256){
    int v = cnt[base + tid];
    int x = v;
    sh[tid] = x; __syncthreads();
    for (int o = 1; o < 256; o <<= 1){
      int y = (tid >= o) ? sh[tid - o] : 0;
      __syncthreads();
      x += y; sh[tid] = x;
      __syncthreads();
    }
    off[base + tid] = carry + x - v;
    __syncthreads();
    if (tid == 255){
      carry += x;
      if (base + 256 == NN) off[NN] = carry;
    }
    __syncthreads();
  }
}
__global__ void k_fill(const int* __restrict__ src, const int* __restrict__ dst,
                       const int* __restrict__ roff, int* cursor, int* csr){
  int e = blockIdx.x*256 + threadIdx.x;
  if (e < NE){
    int d = dst[e];
    int p = atomicAdd(&cursor[d], 1);
    csr[roff[d] + p] = src[e];
  }
}

// ---------------- gconv1 fused (3 -> 256) ----------------
__global__ void k_gconv1(const float* __restrict__ feat, const int* __restrict__ roff,
                         const int* __restrict__ csr, const float* __restrict__ dout,
                         const float* __restrict__ din, const float* __restrict__ Wc1,
                         const float* __restrict__ bc1, float* __restrict__ h1){
  int wid = threadIdx.x >> 6, lane = threadIdx.x & 63;
  int i = blockIdx.x*4 + wid;
  float a0=0.f, a1=0.f, a2=0.f;
  int beg = roff[i], end = roff[i+1];
  for (int t = beg + lane; t < end; t += 64){
    int s = csr[t]; float w = dout[s];
    a0 += feat[s*3+0]*w; a1 += feat[s*3+1]*w; a2 += feat[s*3+2]*w;
  }
  for (int m = 32; m; m >>= 1){
    a0 += __shfl_xor(a0, m); a1 += __shfl_xor(a1, m); a2 += __shfl_xor(a2, m);
  }
  float dn = din[i];
  a0 *= dn; a1 *= dn; a2 *= dn;
  for (int c = lane; c < 256; c += 64){
    float r = a0*Wc1[c] + a1*Wc1[256+c] + a2*Wc1[512+c] + bc1[c];
    h1[(size_t)i*256 + c] = fmaxf(r, 0.f);
  }
}

// ---------------- row squared norms (C=256) ----------------
__global__ void k_sq(const float* __restrict__ X, float* __restrict__ sq){
  int wid = threadIdx.x >> 6, lane = threadIdx.x & 63;
  int i = blockIdx.x*4 + wid;
  float4 v = *(const float4*)&X[(size_t)i*256 + lane*4];
  float s = v.x*v.x + v.y*v.y + v.z*v.z + v.w*v.w;
  for (int m = 32; m; m >>= 1) s += __shfl_xor(s, m);
  if (lane == 0) sq[i] = s;
}

// ---------------- split f32 -> [hi|lo] bf16, Xcat[n][512] ----------------
__global__ void k_split(const float* __restrict__ X, unsigned short* __restrict__ xcat){
  int row = blockIdx.x, c = threadIdx.x;
  float x = X[(size_t)row*256 + c];
  unsigned short h = f2bf(x);
  unsigned short lo = f2bf(x - bf2f(h));
  xcat[(size_t)row*512 + c] = h;
  xcat[(size_t)row*512 + 256 + c] = lo;
}

// ---------------- MFMA gram: G[chunk row][j] = x_i . x_j (split bf16, K=768) ----------------
// A sections: {hi, lo, hi}; B sections: {hi, hi, lo}
__global__ __launch_bounds__(256)
void k_gram_mfma(const unsigned short* __restrict__ Xcat,
                 float* __restrict__ G, int r0){
  __shared__ unsigned short sA[GBM*GBK];  // 16 KB, swizzled granules
  __shared__ unsigned short sB[GBN*GBK];
  int tid = threadIdx.x;
  int lw = tid >> 6, l = tid & 63;
  int rbl = blockIdx.y*GBM;      // local chunk row base
  int rb = r0 + rbl;             // global source row base (A)
  int cb = blockIdx.x*GBN;       // global source row base (B) = G column base

  int srow = l >> 3;             // 0..7
  int scol = (l & 7) ^ srow;     // swizzled source granule (row&7 == srow)
  const unsigned short* srcA[4];
  const unsigned short* srcB[4];
  char* dstA[4]; char* dstB[4];
  #pragma unroll
  for (int i = 0; i < 4; i++){
    int c = lw*4 + i;
    int row = c*8 + srow;
    srcA[i] = Xcat + (size_t)(rb + row)*512 + scol*8;
    srcB[i] = Xcat + (size_t)(cb + row)*512 + scol*8;
    dstA[i] = (char*)sA + c*1024;
    dstB[i] = (char*)sB + c*1024;
  }

  int wm = lw >> 1, wn = lw & 1;
  int fm = l & 15, kg = l >> 4;
  unsigned offA[4][2], offB[4][2];
  #pragma unroll
  for (int mf = 0; mf < 4; mf++){
    int rowa = wm*64 + mf*16 + fm;
    int rowb = wn*64 + mf*16 + fm;
    #pragma unroll
    for (int ks = 0; ks < 2; ks++){
      offA[mf][ks] = rowa*128 + (((unsigned)(ks*4 + kg) ^ (rowa & 7)))*16;
      offB[mf][ks] = rowb*128 + (((unsigned)(ks*4 + kg) ^ (rowb & 7)))*16;
    }
  }

  f32x4 acc[4][4];
  #pragma unroll
  for (int m = 0; m < 4; m++)
    #pragma unroll
    for (int n = 0; n < 4; n++) acc[m][n] = (f32x4){0.f,0.f,0.f,0.f};

  #pragma unroll
  for (int s = 0; s < 12; s++){
    int sec = s >> 2;
    int inner = (s & 3)*64;
    int cbA = (sec == 1 ? 256 : 0) + inner;
    int cbB = (sec == 2 ? 256 : 0) + inner;
    #pragma unroll
    for (int i = 0; i < 4; i++){
      gload16(srcA[i] + cbA, dstA[i]);
      gload16(srcB[i] + cbB, dstB[i]);
    }
    __syncthreads();
    #pragma unroll
    for (int ks = 0; ks < 2; ks++){
      bf16x8 a[4], b[4];
      #pragma unroll
      for (int mf = 0; mf < 4; mf++) a[mf] = *(const bf16x8*)((const char*)sA + offA[mf][ks]);
      #pragma unroll
      for (int nf = 0; nf < 4; nf++) b[nf] = *(const bf16x8*)((const char*)sB + offB[nf][ks]);
      #pragma unroll
      for (int mf = 0; mf < 4; mf++)
        #pragma unroll
        for (int nf = 0; nf < 4; nf++)
          acc[mf][nf] = __builtin_amdgcn_mfma_f32_16x16x32_bf16(a[mf], b[nf], acc[mf][nf], 0, 0, 0);
    }
    __syncthreads();
  }

  #pragma unroll
  for (int mf = 0; mf < 4; mf++){
    int orow = rbl + wm*64 + mf*16 + kg*4;
    #pragma unroll
    for (int nf = 0; nf < 4; nf++){
      int ocol = cb + wn*64 + nf*16 + fm;
      #pragma unroll
      for (int r = 0; r < 4; r++)
        G[(size_t)(orow + r)*NN + ocol] = acc[mf][nf][r];
    }
  }
}

// ---------------- top-K per row: compact rolled scan + wave-threshold filter ----------------
// Exactness: T = min over lanes of kd[19] is an upper bound on the global 20th
// smallest. Any element of the final top-20 has key <= final 20th <= T at all
// times, so it always passes the filter; it can only be evicted from a lane list
// by 20 composite-smaller elements in that lane, which would already exclude it
// from the global top-20. In-lane strict-< insertion is stable (later-scanned
// equal values have larger idx); cross-lane merge uses (val,idx) compare.
// NOTE: outer loop deliberately NOT unrolled (unroll 1) — full unroll made the
// body ~60-80 KB and thrashed the 32 KB I-cache (R3 post-mortem).
__global__ __launch_bounds__(256)
void k_topk(const float* __restrict__ G, const float* __restrict__ sq,
            int r0, int* __restrict__ idxo){
  __shared__ float lsq[NN];   // 32 KB: sq staged once per block
  int tid = threadIdx.x;
  for (int t = tid; t < NN/4; t += 256)
    ((float4*)lsq)[t] = ((const float4*)sq)[t];
  __syncthreads();

  int wid = tid >> 6, lane = tid & 63;
  int rl = blockIdx.x*4 + wid;
  int gr = r0 + rl;
  const float4* row4 = (const float4*)(G + (size_t)rl*NN);
  float sqr = lsq[gr];

  float kd[KNN]; int ki[KNN];
  #pragma unroll
  for (int u = 0; u < KNN; u++){ kd[u] = INFINITY; ki[u] = 0x7fffffff; }
  float T = INFINITY;

  float4 cur[4], nxt[4];
  #pragma unroll
  for (int q = 0; q < 4; q++) cur[q] = row4[lane + q*64];

  #pragma unroll 1
  for (int o = 0; o < 8; o++){
    if (o < 7){
      #pragma unroll
      for (int q = 0; q < 4; q++) nxt[q] = row4[lane + (o+1)*256 + q*64];
    }
    #pragma unroll
    for (int q = 0; q < 4; q++){
      float4 g = cur[q];
      int jb = 4*lane + (o*4 + q)*256;
      float4 s = *(const float4*)&lsq[jb];
      float k0 = (sqr + s.x) - 2.f*g.x;
      float k1 = (sqr + s.y) - 2.f*g.y;
      float k2 = (sqr + s.z) - 2.f*g.z;
      float k3 = (sqr + s.w) - 2.f*g.w;
      float mn = fminf(fminf(k0,k1), fminf(k2,k3));
      if (__any(mn <= T)){
        #pragma unroll
        for (int e = 0; e < 4; e++){
          float kc = e==0 ? k0 : (e==1 ? k1 : (e==2 ? k2 : k3));
          if (kc <= T){
            float nk = kc; int ni = jb + e;
            #pragma unroll
            for (int u = 0; u < KNN; u++){
              bool sw = nk < kd[u];
              float tv = kd[u]; int ti = ki[u];
              if (sw){ kd[u] = nk; ki[u] = ni; nk = tv; ni = ti; }
            }
          }
        }
        float tt = kd[KNN-1];
        #pragma unroll
        for (int mm = 32; mm; mm >>= 1) tt = fminf(tt, __shfl_xor(tt, mm));
        T = tt;
      }
    }
    #pragma unroll
    for (int q = 0; q < 4; q++) cur[q] = nxt[q];
  }

  // cross-lane merge: 20 rounds of wave argmin on (val, idx)
  for (int r = 0; r < KNN; r++){
    float cv = kd[0]; int ci = ki[0]; int cl = lane;
    for (int m = 32; m; m >>= 1){
      float ov = __shfl_xor(cv, m); int oi = __shfl_xor(ci, m); int ol = __shfl_xor(cl, m);
      if (ov < cv || (ov == cv && oi < ci)){ cv = ov; ci = oi; cl = ol; }
    }
    if (lane == cl){
      #pragma unroll
      for (int u = 0; u < KNN-1; u++){ kd[u] = kd[u+1]; ki[u] = ki[u+1]; }
      kd[KNN-1] = INFINITY; ki[KNN-1] = 0x7fffffff;
    }
    if (lane == 0) idxo[(size_t)gr*KNN + r] = ci;
  }
}

// ---------------- Wd = Wtop - Wbot ----------------
__global__ void k_wd(const float* __restrict__ W, float* __restrict__ Wd, int rows, int M){
  int t = blockIdx.x*256 + threadIdx.x;
  if (t < rows*M) Wd[t] = W[t] - W[rows*M + t];
}

// ---------------- generic tiled matmul: C = A(nxK) @ B(KxM) [+bias][relu] ----------------
__global__ __launch_bounds__(256)
void k_mm(const float* __restrict__ A, const float* __restrict__ B,
          const float* __restrict__ bias, float* __restrict__ Cout,
          int n, int Kd, int M, int relu){
  __shared__ float la[16][68], lb[16][68];
  int tid = threadIdx.x;
  int rb = blockIdx.y*64, cb = blockIdx.x*64;
  int lr = tid >> 2, lq = (tid & 3)*4;
  int ty = tid >> 4, tx = tid & 15;
  float acc[4][4] = {};
  for (int k0 = 0; k0 < Kd; k0 += 16){
    __syncthreads();
    #pragma unroll
    for (int u = 0; u < 4; u++){
      int k = k0 + lq + u;
      la[lq+u][lr] = (k < Kd) ? A[(size_t)(rb+lr)*Kd + k] : 0.f;
    }
    int kk = tid >> 4; int cc = (tid & 15)*4;
    #pragma unroll
    for (int u = 0; u < 4; u++){
      int c = cb + cc + u; int k = k0 + kk;
      lb[kk][cc+u] = (k < Kd && c < M) ? B[(size_t)k*M + c] : 0.f;
    }
    __syncthreads();
    #pragma unroll
    for (int k = 0; k < 16; k++){
      float4 a = *(const float4*)&la[k][ty*4];
      float4 b = *(const float4*)&lb[k][tx*4];
      float avv[4] = {a.x,a.y,a.z,a.w}, bvv[4] = {b.x,b.y,b.z,b.w};
      #pragma unroll
      for (int u = 0; u < 4; u++)
        #pragma unroll
        for (int v = 0; v < 4; v++) acc[u][v] += avv[u]*bvv[v];
    }
  }
  #pragma unroll
  for (int u = 0; u < 4; u++){
    int r = rb + ty*4 + u;
    #pragma unroll
    for (int v = 0; v < 4; v++){
      int c = cb + tx*4 + v;
      if (c < M){
        float x = acc[u][v] + (bias ? bias[c] : 0.f);
        if (relu) x = fmaxf(x, 0.f);
        Cout[(size_t)r*M + c] = x;
      }
    }
  }
}

// ---------------- stats over A[i]+P[j] per channel ----------------
template<int C>
__global__ __launch_bounds__(256)
void k_stats1(const float* __restrict__ A, const float* __restrict__ P,
              const int* __restrict__ idx, float* __restrict__ ssum, float* __restrict__ ssq){
  __shared__ int si[128], sj[128];
  int tid = threadIdx.x;
  int s0 = blockIdx.x*128;
  if (tid < 128){ si[tid] = (s0 + tid)/KNN; sj[tid] = idx[s0 + tid]; }
  __syncthreads();
  constexpr int MPAR = 256/C;
  int tc = tid % C, sr = tid / C;
  float s = 0.f, q = 0.f;
  for (int m = sr; m < 128; m += MPAR){
    float v = A[(size_t)si[m]*C + tc] + P[(size_t)sj[m]*C + tc];
    s += v; q += v*v;
  }
  if constexpr (MPAR > 1){
    __shared__ float rs[256], rq[256];
    rs[tid] = s; rq[tid] = q; __syncthreads();
    if (sr == 0){
      for (int u = 1; u < MPAR; u++){ s += rs[u*C + tc]; q += rq[u*C + tc]; }
    }
  }
  if (sr == 0){ atomicAdd(&ssum[tc], s); atomicAdd(&ssq[tc], q); }
}

// ---------------- column stats over dense X (rows = N*KNN) ----------------
template<int C>
__global__ __launch_bounds__(256)
void k_colstats(const float* __restrict__ X, float* __restrict__ ssum, float* __restrict__ ssq){
  constexpr int MPAR = 256/C;
  int tid = threadIdx.x;
  int tc = tid % C, sr = tid / C;
  int base = blockIdx.x*256;
  float s = 0.f, q = 0.f;
  for (int m = sr; m < 256; m += MPAR){
    float v = X[(size_t)(base + m)*C + tc];
    s += v; q += v*v;
  }
  if constexpr (MPAR > 1){
    __shared__ float rs[256], rq[256];
    rs[tid] = s; rq[tid] = q; __syncthreads();
    if (sr == 0){
      for (int u = 1; u < MPAR; u++){ s += rs[u*C + tc]; q += rq[u*C + tc]; }
    }
  }
  if (sr == 0){ atomicAdd(&ssum[tc], s); atomicAdd(&ssq[tc], q); }
}

__global__ void k_bn_final(const float* __restrict__ ssum, const float* __restrict__ ssq,
                           const float* __restrict__ g, const float* __restrict__ be,
                           float* __restrict__ sb, float* __restrict__ tb, int C, float invn){
  int c = threadIdx.x;
  if (c < C){
    float mu = ssum[c]*invn;
    float var = fmaxf(ssq[c]*invn - mu*mu, 0.f);
    float s = g[c]*rsqrtf(var + 1e-5f);
    sb[c] = s; tb[c] = be[c] - mu*s;
  }
}

// ---------------- per-edge matmul: out = relu(bn1(A[i]+P[j])) @ W + bias ----------------
template<int C>
__global__ __launch_bounds__(256)
void k_edge_mm(const float* __restrict__ A, const float* __restrict__ P,
               const int* __restrict__ idx, const float* __restrict__ sb,
               const float* __restrict__ tb, const float* __restrict__ W,
               const float* __restrict__ bias, float* __restrict__ out){
  constexpr int BM   = (C == 256) ? 32 : 64;
  constexpr int KT   = (C == 256) ? 16 : 64;
  constexpr int COLG = C/8;
  constexpr int ROWG = 256/COLG;
  constexpr int EPT  = BM/ROWG;
  constexpr int MPAR = 256/C;
  __shared__ float e2[BM][C+1];
  __shared__ float wt[KT][C+4];
  __shared__ int sj[BM];
  int tid = threadIdx.x;
  int s0 = blockIdx.x*BM;
  if (tid < BM) sj[tid] = idx[s0 + tid];
  __syncthreads();
  for (int mb = 0; mb < BM; mb += MPAR){
    int m = mb + tid / C;
    int c = tid % C;
    int i = (s0 + m)/KNN;
    int j = sj[m];
    float v = (A[(size_t)i*C + c] + P[(size_t)j*C + c])*sb[c] + tb[c];
    e2[m][c] = fmaxf(v, 0.f);
  }
  float acc[EPT][8];
  #pragma unroll
  for (int m = 0; m < EPT; m++)
    #pragma unroll
    for (int u = 0; u < 8; u++) acc[m][u] = 0.f;
  int tr = tid / COLG, tc = tid % COLG;
  for (int kt = 0; kt < C; kt += KT){
    __syncthreads();
    for (int t = tid; t < KT*C; t += 256){
      wt[t / C][t % C] = W[(size_t)(kt + t/C)*C + (t % C)];
    }
    __syncthreads();
    #pragma unroll 4
    for (int k = 0; k < KT; k++){
      float4 w0 = *(const float4*)&wt[k][tc*8];
      float4 w1 = *(const float4*)&wt[k][tc*8 + 4];
      float b[8] = {w0.x,w0.y,w0.z,w0.w,w1.x,w1.y,w1.z,w1.w};
      #pragma unroll
      for (int m = 0; m < EPT; m++){
        float a = e2[tr*EPT + m][kt + k];
        #pragma unroll
        for (int u = 0; u < 8; u++) acc[m][u] += a*b[u];
      }
    }
  }
  #pragma unroll
  for (int m = 0; m < EPT; m++){
    int row = s0 + tr*EPT + m;
    float4 o0, o1;
    o0.x = acc[m][0] + bias[tc*8+0]; o0.y = acc[m][1] + bias[tc*8+1];
    o0.z = acc[m][2] + bias[tc*8+2]; o0.w = acc[m][3] + bias[tc*8+3];
    o1.x = acc[m][4] + bias[tc*8+4]; o1.y = acc[m][5] + bias[tc*8+5];
    o1.z = acc[m][6] + bias[tc*8+6]; o1.w = acc[m][7] + bias[tc*8+7];
    *(float4*)&out[(size_t)row*C + tc*8]     = o0;
    *(float4*)&out[(size_t)row*C + tc*8 + 4] = o1;
  }
}

// ---------------- bn2 + relu + max over K ----------------
template<int C>
__global__ void k_maxpool(const float* __restrict__ X, const float* __restrict__ sb,
                          const float* __restrict__ tb, float* __restrict__ H){
  constexpr int NPB = 256/C;
  int node = blockIdx.x*NPB + threadIdx.x / C;
  int c = threadIdx.x % C;
  float s = sb[c], t = tb[c];
  float mx = 0.f;
  for (int k = 0; k < KNN; k++){
    float v = X[(size_t)(node*KNN + k)*C + c]*s + t;
    mx = fmaxf(mx, v);
  }
  H[(size_t)node*C + c] = mx;
}

// ---------------- gconv aggregation ----------------
template<int C>
__global__ void k_agg(const float* __restrict__ X, const int* __restrict__ roff,
                      const int* __restrict__ csr, const float* __restrict__ dout,
                      const float* __restrict__ din, float* __restrict__ XA){
  int i = blockIdx.x; int c = threadIdx.x;
  float acc = 0.f;
  int b = roff[i], e = roff[i+1];
  for (int t = b; t < e; t++){
    int s = csr[t];
    acc += X[(size_t)s*C + c]*dout[s];
  }
  XA[(size_t)i*C + c] = acc*din[i];
}

// ================= host =================
extern "C" void kernel_launch(void* const* d_in, const int* in_sizes, int n_in,
                              void* d_out, int out_size, void* d_ws, size_t ws_size,
                              hipStream_t stream){
  const float* feat = (const float*)d_in[0];
  const int*   src  = (const int*)d_in[1];
  const int*   dst  = (const int*)d_in[2];
  const float* Wc1  = (const float*)d_in[3];
  const float* bc1  = (const float*)d_in[4];
  const float* Wc2  = (const float*)d_in[5];
  const float* bc2  = (const float*)d_in[6];
  const float* Wc3  = (const float*)d_in[7];
  const float* bc3  = (const float*)d_in[8];
  const float* W11  = (const float*)d_in[9];
  const float* b11  = (const float*)d_in[10];
  const float* g11  = (const float*)d_in[11];
  const float* be11 = (const float*)d_in[12];
  const float* W12  = (const float*)d_in[13];
  const float* b12  = (const float*)d_in[14];
  const float* g12  = (const float*)d_in[15];
  const float* be12 = (const float*)d_in[16];
  const float* W21  = (const float*)d_in[17];
  const float* b21  = (const float*)d_in[18];
  const float* g21  = (const float*)d_in[19];
  const float* be21 = (const float*)d_in[20];
  const float* W22  = (const float*)d_in[21];
  const float* b22  = (const float*)d_in[22];
  const float* g22  = (const float*)d_in[23];
  const float* be22 = (const float*)d_in[24];
  float* out = (float*)d_out;

  char* w = (char*)d_ws; size_t off = 0;
  auto alloc = [&](size_t bytes)->void*{
    void* p = w + off;
    off += bytes; off = (off + 255) & ~(size_t)255;
    return p;
  };
  int* cnt_s  = (int*)alloc(NN*4);
  int* cnt_d  = (int*)alloc(NN*4);
  int* roff   = (int*)alloc((NN+1)*4);
  int* cursor = (int*)alloc(NN*4);
  int* csr    = (int*)alloc(NE*4);
  int* idx    = (int*)alloc((size_t)NN*KNN*4);
  float* dout = (float*)alloc(NN*4);
  float* din  = (float*)alloc(NN*4);
  float* sqv  = (float*)alloc(NN*4);
  float* h1   = (float*)alloc((size_t)NN*256*4);
  float* h2   = (float*)alloc((size_t)NN*256*4);
  float* h3   = (float*)alloc((size_t)NN*256*4);
  float* h4   = (float*)alloc((size_t)NN*64*4);
  float* xa   = (float*)alloc((size_t)NN*256*4);
  float* Abuf = (float*)alloc((size_t)NN*256*4);
  float* Pbuf = (float*)alloc((size_t)NN*256*4);
  float* Wd   = (float*)alloc(256*256*4);
  float* ssum = (float*)alloc(256*4);
  float* ssq  = (float*)alloc(256*4);
  float* sbn  = (float*)alloc(256*4);
  float* tbn  = (float*)alloc(256*4);
  float* out2 = (float*)alloc((size_t)NN*KNN*256*4);   // 167.8 MB
  // kNN scratch aliases out2 (consumed before edge_mm writes out2):
  float* gram = out2;                                        // CH*NN*4 = 134.2 MB
  unsigned short* xcat = (unsigned short*)(out2 + (size_t)CH*NN);  // 8.4 MB
  (void)ws_size; (void)n_in; (void)in_sizes; (void)out_size;

  const float invn = 1.0f / (float)(NN*KNN);

  // graph prep
  k_zero_i<<<32, 256, 0, stream>>>(cnt_s, NN);
  k_zero_i<<<32, 256, 0, stream>>>(cnt_d, NN);
  k_zero_i<<<32, 256, 0, stream>>>(cursor, NN);
  k_count<<<NE/256, 256, 0, stream>>>(src, dst, cnt_s, cnt_d);
  k_deg<<<32, 256, 0, stream>>>(cnt_s, cnt_d, dout, din);
  k_scan<<<1, 256, 0, stream>>>(cnt_d, roff);
  k_fill<<<NE/256, 256, 0, stream>>>(src, dst, roff, cursor, csr);

  // gconv1 -> h1
  k_gconv1<<<NN/4, 256, 0, stream>>>(feat, roff, csr, dout, din, Wc1, bc1, h1);

  // ---- edge conv 1 (input h1, 256 -> 256 -> 256) ----
  k_sq<<<NN/4, 256, 0, stream>>>(h1, sqv);
  k_split<<<NN, 256, 0, stream>>>(h1, xcat);
  for (int r0 = 0; r0 < NN; r0 += CH){
    k_gram_mfma<<<dim3(NN/GBN, CH/GBM), 256, 0, stream>>>(xcat, gram, r0);
    k_topk<<<CH/4, 256, 0, stream>>>(gram, sqv, r0, idx);
  }
  k_wd<<<256, 256, 0, stream>>>(W11, Wd, 256, 256);
  k_mm<<<dim3(4, NN/64), 256, 0, stream>>>(h1, Wd, b11, Abuf, NN, 256, 256, 0);
  k_mm<<<dim3(4, NN/64), 256, 0, stream>>>(h1, W11 + 256*256, nullptr, Pbuf, NN, 256, 256, 0);
  k_zero<<<2, 256, 0, stream>>>(ssum, 256); k_zero<<<2, 256, 0, stream>>>(ssq, 256);
  k_stats1<256><<<NN*KNN/128, 256, 0, stream>>>(Abuf, Pbuf, idx, ssum, ssq);
  k_bn_final<<<1, 256, 0, stream>>>(ssum, ssq, g11, be11, sbn, tbn, 256, invn);
  k_edge_mm<256><<<NN*KNN/32, 256, 0, stream>>>(Abuf, Pbuf, idx, sbn, tbn, W12, b12, out2);
  k_zero<<<2, 256, 0, stream>>>(ssum, 256); k_zero<<<2, 256, 0, stream>>>(ssq, 256);
  k_colstats<256><<<NN*KNN/256, 256, 0, stream>>>(out2, ssum, ssq);
  k_bn_final<<<1, 256, 0, stream>>>(ssum, ssq, g12, be12, sbn, tbn, 256, invn);
  k_maxpool<256><<<NN, 256, 0, stream>>>(out2, sbn, tbn, h2);

  // gconv2 -> h3
  k_agg<256><<<NN, 256, 0, stream>>>(h2, roff, csr, dout, din, xa);
  k_mm<<<dim3(4, NN/64), 256, 0, stream>>>(xa, Wc2, bc2, h3, NN, 256, 256, 1);

  // ---- edge conv 2 (input h3, 256 -> 64 -> 64) ----
  k_sq<<<NN/4, 256, 0, stream>>>(h3, sqv);
  k_split<<<NN, 256, 0, stream>>>(h3, xcat);
  for (int r0 = 0; r0 < NN; r0 += CH){
    k_gram_mfma<<<dim3(NN/GBN, CH/GBM), 256, 0, stream>>>(xcat, gram, r0);
    k_topk<<<CH/4, 256, 0, stream>>>(gram, sqv, r0, idx);
  }
  k_wd<<<64, 256, 0, stream>>>(W21, Wd, 256, 64);
  k_mm<<<dim3(1, NN/64), 256, 0, stream>>>(h3, Wd, b21, Abuf, NN, 256, 64, 0);
  k_mm<<<dim3(1, NN/64), 256, 0, stream>>>(h3, W21 + 256*64, nullptr, Pbuf, NN, 256, 64, 0);
  k_zero<<<2, 256, 0, stream>>>(ssum, 256); k_zero<<<2, 256, 0, stream>>>(ssq, 256);
  k_stats1<64><<<NN*KNN/128, 256, 0, stream>>>(Abuf, Pbuf, idx, ssum, ssq);
  k_bn_final<<<1, 256, 0, stream>>>(ssum, ssq, g21, be21, sbn, tbn, 64, invn);
  k_edge_mm<64><<<NN*KNN/64, 256, 0, stream>>>(Abuf, Pbuf, idx, sbn, tbn, W22, b22, out2);
  k_zero<<<2, 256, 0, stream>>>(ssum, 256); k_zero<<<2, 256, 0, stream>>>(ssq, 256);
  k_colstats<64><<<NN*KNN/256, 256, 0, stream>>>(out2, ssum, ssq);
  k_bn_final<<<1, 256, 0, stream>>>(ssum, ssq, g22, be22, sbn, tbn, 64, invn);
  k_maxpool<64><<<NN/4, 256, 0, stream>>>(out2, sbn, tbn, h4);

  // gconv3 -> out
  k_agg<64><<<NN, 64, 0, stream>>>(h4, roff, csr, dout, din, xa);
  k_mm<<<dim3(1, NN/64), 256, 0, stream>>>(xa, Wc3, bc3, out, NN, 64, 32, 0);
}

// Round 5
// 4477.462 us; speedup vs baseline: 2.2131x; 1.2763x over previous
//
#include <hip/hip_runtime.h>

#define NN 8192
#define NE 131072
#define KNN 20
#define GBM 128
#define GBK 64
#define SPL 8            // kNN column splits
#define CPS (NN/SPL)     // 1024 cols per split

typedef __attribute__((ext_vector_type(4))) float f32x4;
typedef __attribute__((ext_vector_type(8))) __bf16 bf16x8;

// ---------------- utility ----------------
__global__ void k_zero(float* p, int n){
  int i = blockIdx.x*256 + threadIdx.x;
  if (i < n) p[i] = 0.f;
}
__global__ void k_zero_i(int* p, int n){
  int i = blockIdx.x*256 + threadIdx.x;
  if (i < n) p[i] = 0;
}

__device__ __forceinline__ unsigned short f2bf(float x){
  unsigned u = __float_as_uint(x);
  unsigned r = (u + 0x7fff + ((u >> 16) & 1)) >> 16;
  return (unsigned short)r;
}
__device__ __forceinline__ float bf2f(unsigned short h){
  return __uint_as_float((unsigned)h << 16);
}
__device__ __forceinline__ void gload16(const void* g, void* l){
  __builtin_amdgcn_global_load_lds(
      (const __attribute__((address_space(1))) void*)g,
      (__attribute__((address_space(3))) void*)l, 16, 0, 0);
}

// ---------------- graph prep ----------------
__global__ void k_count(const int* __restrict__ src, const int* __restrict__ dst,
                        int* cs, int* cd){
  int e = blockIdx.x*256 + threadIdx.x;
  if (e < NE){ atomicAdd(&cs[src[e]], 1); atomicAdd(&cd[dst[e]], 1); }
}
__global__ void k_deg(const int* cs, const int* cd, float* dout, float* din){
  int i = blockIdx.x*256 + threadIdx.x;
  if (i < NN){
    dout[i] = rsqrtf((float)max(cs[i], 1));
    din[i]  = rsqrtf((float)max(cd[i], 1));
  }
}
__global__ void k_scan(const int* __restrict__ cnt, int* __restrict__ off){
  __shared__ int sh[256];
  __shared__ int carry;
  int tid = threadIdx.x;
  if (tid == 0) carry = 0;
  __syncthreads();
  for (int base = 0; base < NN; base += 256){
    int v = cnt[base + tid];
    int x = v;
    sh[tid] = x; __syncthreads();
    for (int o = 1; o < 256; o <<= 1){
      int y = (tid >= o) ? sh[tid - o] : 0;
      __syncthreads();
      x += y; sh[tid] = x;
      __syncthreads();
    }
    off[base + tid] = carry + x - v;
    __syncthreads();
    if (tid == 255){
      carry += x;
      if (base + 256 == NN) off[NN] = carry;
    }
    __syncthreads();
  }
}
__global__ void k_fill(const int* __restrict__ src, const int* __restrict__ dst,
                       const int* __restrict__ roff, int* cursor, int* csr){
  int e = blockIdx.x*256 + threadIdx.x;
  if (e < NE){
    int d = dst[e];
    int p = atomicAdd(&cursor[d], 1);
    csr[roff[d] + p] = src[e];
  }
}

// ---------------- gconv1 fused (3 -> 256) ----------------
__global__ void k_gconv1(const float* __restrict__ feat, const int* __restrict__ roff,
                         const int* __restrict__ csr, const float* __restrict__ dout,
                         const float* __restrict__ din, const float* __restrict__ Wc1,
                         const float* __restrict__ bc1, float* __restrict__ h1){
  int wid = threadIdx.x >> 6, lane = threadIdx.x & 63;
  int i = blockIdx.x*4 + wid;
  float a0=0.f, a1=0.f, a2=0.f;
  int beg = roff[i], end = roff[i+1];
  for (int t = beg + lane; t < end; t += 64){
    int s = csr[t]; float w = dout[s];
    a0 += feat[s*3+0]*w; a1 += feat[s*3+1]*w; a2 += feat[s*3+2]*w;
  }
  for (int m = 32; m; m >>= 1){
    a0 += __shfl_xor(a0, m); a1 += __shfl_xor(a1, m); a2 += __shfl_xor(a2, m);
  }
  float dn = din[i];
  a0 *= dn; a1 *= dn; a2 *= dn;
  for (int c = lane; c < 256; c += 64){
    float r = a0*Wc1[c] + a1*Wc1[256+c] + a2*Wc1[512+c] + bc1[c];
    h1[(size_t)i*256 + c] = fmaxf(r, 0.f);
  }
}

// ---------------- row squared norms (C=256) ----------------
__global__ void k_sq(const float* __restrict__ X, float* __restrict__ sq){
  int wid = threadIdx.x >> 6, lane = threadIdx.x & 63;
  int i = blockIdx.x*4 + wid;
  float4 v = *(const float4*)&X[(size_t)i*256 + lane*4];
  float s = v.x*v.x + v.y*v.y + v.z*v.z + v.w*v.w;
  for (int m = 32; m; m >>= 1) s += __shfl_xor(s, m);
  if (lane == 0) sq[i] = s;
}

// ---------------- split f32 -> [hi|lo] bf16, Xcat[n][512] ----------------
__global__ void k_split(const float* __restrict__ X, unsigned short* __restrict__ xcat){
  int row = blockIdx.x, c = threadIdx.x;
  float x = X[(size_t)row*256 + c];
  unsigned short h = f2bf(x);
  unsigned short lo = f2bf(x - bf2f(h));
  xcat[(size_t)row*512 + c] = h;
  xcat[(size_t)row*512 + 256 + c] = lo;
}

// ---------------- FUSED gram + top-K partial selection ----------------
// Block: 128 rows x one 1024-col split. Per 128x128 col-tile: MFMA (split-bf16,
// K=768, A={hi,lo,hi} B={hi,hi,lo}) -> keys into LDS tile -> per-lane running
// sorted top-20 (lane owns (row, half-row); guard = own kd[19]).
// Exactness: any true row-top-20 element has <=19 subset elements smaller, so it
// survives in its lane's top-20; pooling lane lists loses nothing. In-lane
// strict-< insertion is tie-stable (ascending col order); cross-subset ties are
// resolved in the merge kernel via (val,idx).
__global__ __launch_bounds__(256, 1)
void k_gramtopk(const unsigned short* __restrict__ Xcat, const float* __restrict__ sq,
                float* __restrict__ pd, int* __restrict__ pi){
  __shared__ unsigned short sA[GBM*GBK];   // 16 KB, swizzled granules
  __shared__ unsigned short sB[GBM*GBK];   // 16 KB
  __shared__ float tile[GBM][132];         // 67.6 KB keys
  __shared__ float sqr[GBM];
  __shared__ float sqc[128];

  int tid = threadIdx.x;
  int lw = tid >> 6, l = tid & 63;
  int rb = blockIdx.y*GBM;
  int split = blockIdx.x;
  int cb0 = split*CPS;

  if (tid < GBM) sqr[tid] = sq[rb + tid];

  // staging source constants (per gload a wave writes 1KB = 8 rows x 8 granules)
  int srow = l >> 3;
  int scol = (l & 7) ^ srow;
  const unsigned short* srcA[4];
  const unsigned short* srcB[4];
  char* dstA[4]; char* dstB[4];
  #pragma unroll
  for (int i = 0; i < 4; i++){
    int c = lw*4 + i;
    int row = c*8 + srow;
    srcA[i] = Xcat + (size_t)(rb  + row)*512 + scol*8;
    srcB[i] = Xcat + (size_t)(cb0 + row)*512 + scol*8;
    dstA[i] = (char*)sA + c*1024;
    dstB[i] = (char*)sB + c*1024;
  }

  // fragment read offsets (bytes), swizzled: q = col16 ^ (row&7)
  int wm = lw >> 1, wn = lw & 1;
  int fm = l & 15, kg = l >> 4;
  unsigned offA[4][2], offB[4][2];
  #pragma unroll
  for (int mf = 0; mf < 4; mf++){
    int rowa = wm*64 + mf*16 + fm;
    int rowb = wn*64 + mf*16 + fm;
    #pragma unroll
    for (int ks = 0; ks < 2; ks++){
      offA[mf][ks] = rowa*128 + (((unsigned)(ks*4 + kg) ^ (rowa & 7)))*16;
      offB[mf][ks] = rowb*128 + (((unsigned)(ks*4 + kg) ^ (rowb & 7)))*16;
    }
  }

  // per-lane top-20 state: lane owns (row = lw*32 + l/2, half = l&1)
  int myrow = lw*32 + (l >> 1);
  int myhalf = l & 1;
  float kd[KNN]; int ki[KNN];
  #pragma unroll
  for (int u = 0; u < KNN; u++){ kd[u] = INFINITY; ki[u] = 0x7fffffff; }

  #pragma unroll 1
  for (int ct = 0; ct < CPS/128; ct++){
    if (tid < 128) sqc[tid] = sq[cb0 + ct*128 + tid];

    f32x4 acc[4][4];
    #pragma unroll
    for (int m = 0; m < 4; m++)
      #pragma unroll
      for (int n = 0; n < 4; n++) acc[m][n] = (f32x4){0.f,0.f,0.f,0.f};

    #pragma unroll
    for (int s = 0; s < 12; s++){
      int sec = s >> 2;
      int inner = (s & 3)*64;
      int cbA = (sec == 1 ? 256 : 0) + inner;
      int cbB = (sec == 2 ? 256 : 0) + inner;
      #pragma unroll
      for (int i = 0; i < 4; i++){
        gload16(srcA[i] + cbA, dstA[i]);
        gload16(srcB[i] + cbB, dstB[i]);
      }
      __syncthreads();
      #pragma unroll
      for (int ks = 0; ks < 2; ks++){
        bf16x8 a[4], b[4];
        #pragma unroll
        for (int mf = 0; mf < 4; mf++) a[mf] = *(const bf16x8*)((const char*)sA + offA[mf][ks]);
        #pragma unroll
        for (int nf = 0; nf < 4; nf++) b[nf] = *(const bf16x8*)((const char*)sB + offB[nf][ks]);
        #pragma unroll
        for (int mf = 0; mf < 4; mf++)
          #pragma unroll
          for (int nf = 0; nf < 4; nf++)
            acc[mf][nf] = __builtin_amdgcn_mfma_f32_16x16x32_bf16(a[mf], b[nf], acc[mf][nf], 0, 0, 0);
      }
      __syncthreads();
    }
    #pragma unroll
    for (int i = 0; i < 4; i++) srcB[i] += 128*512;   // next tile's B rows

    // epilogue: keys into LDS tile. C/D: col = lane&15, row = (lane>>4)*4 + reg
    #pragma unroll
    for (int mf = 0; mf < 4; mf++){
      int orow = wm*64 + mf*16 + kg*4;
      #pragma unroll
      for (int nf = 0; nf < 4; nf++){
        int ocol = wn*64 + nf*16 + fm;
        float sc = sqc[ocol];
        #pragma unroll
        for (int r = 0; r < 4; r++)
          tile[orow + r][ocol] = (sqr[orow + r] + sc) - 2.f*acc[mf][nf][r];
      }
    }
    __syncthreads();

    // scan: 16 steps x 4 keys per lane (keep rolled — I-cache, R3 lesson)
    int jb0 = cb0 + ct*128 + myhalf*64;
    #pragma unroll 1
    for (int st = 0; st < 16; st++){
      float4 kv = *(const float4*)&tile[myrow][myhalf*64 + st*4];
      float ke0 = kv.x, ke1 = kv.y, ke2 = kv.z, ke3 = kv.w;
      int jb = jb0 + st*4;
      int done = 0;
      float m = INFINITY; int sel = -1;
      {
        float t19 = kd[KNN-1];
        if (ke0 < t19 && ke0 < m){ m = ke0; sel = 0; }
        if (ke1 < t19 && ke1 < m){ m = ke1; sel = 1; }
        if (ke2 < t19 && ke2 < m){ m = ke2; sel = 2; }
        if (ke3 < t19 && ke3 < m){ m = ke3; sel = 3; }
      }
      while (__any(sel >= 0)){
        if (sel >= 0){
          float nk = m; int ni = jb + sel;
          #pragma unroll
          for (int u = 0; u < KNN; u++){
            bool sw = nk < kd[u];
            float tv = kd[u]; int ti = ki[u];
            if (sw){ kd[u] = nk; ki[u] = ni; nk = tv; ni = ti; }
          }
          done |= (1 << sel);
        }
        m = INFINITY; sel = -1;
        {
          float t19 = kd[KNN-1];
          if (!(done & 1) && ke0 < t19 && ke0 < m){ m = ke0; sel = 0; }
          if (!(done & 2) && ke1 < t19 && ke1 < m){ m = ke1; sel = 1; }
          if (!(done & 4) && ke2 < t19 && ke2 < m){ m = ke2; sel = 2; }
          if (!(done & 8) && ke3 < t19 && ke3 < m){ m = ke3; sel = 3; }
        }
      }
    }
    __syncthreads();
  }

  // write partial lists: pd[row][split][half][20]
  size_t base = ((size_t)(rb + myrow)*SPL + split)*40 + myhalf*20;
  #pragma unroll
  for (int u = 0; u < KNN; u++){ pd[base + u] = kd[u]; pi[base + u] = ki[u]; }
}

// ---------------- merge partial lists -> exact top-20 per row ----------------
#define CSWAP(va,ia,vb,ib) { if (va > vb || (va == vb && ia > ib)){ \
    float tv = va; va = vb; vb = tv; int ti = ia; ia = ib; ib = ti; } }
__global__ __launch_bounds__(256)
void k_knn_merge(const float* __restrict__ pd, const int* __restrict__ pi,
                 int* __restrict__ idxo){
  int tid = threadIdx.x, lw = tid >> 6, l = tid & 63;
  int row = blockIdx.x*4 + lw;
  size_t base = (size_t)row*(SPL*40) + l*5;
  float v0 = pd[base+0], v1 = pd[base+1], v2 = pd[base+2], v3 = pd[base+3], v4 = pd[base+4];
  int   i0 = pi[base+0], i1 = pi[base+1], i2 = pi[base+2], i3 = pi[base+3], i4 = pi[base+4];
  // sort-5 ascending by (val,idx)
  CSWAP(v0,i0,v1,i1); CSWAP(v3,i3,v4,i4); CSWAP(v2,i2,v4,i4);
  CSWAP(v2,i2,v3,i3); CSWAP(v1,i1,v4,i4); CSWAP(v0,i0,v3,i3);
  CSWAP(v0,i0,v2,i2); CSWAP(v1,i1,v3,i3); CSWAP(v1,i1,v2,i2);
  #pragma unroll 1
  for (int r = 0; r < KNN; r++){
    float bv = v0; int bi = i0;
    #pragma unroll
    for (int mm = 32; mm; mm >>= 1){
      float ov = __shfl_xor(bv, mm); int oi = __shfl_xor(bi, mm);
      if (ov < bv || (ov == bv && oi < bi)){ bv = ov; bi = oi; }
    }
    if (i0 == bi){ v0=v1;i0=i1; v1=v2;i1=i2; v2=v3;i2=i3; v3=v4;i3=i4; v4=INFINITY; i4=0x7fffffff; }
    if (l == 0) idxo[(size_t)row*KNN + r] = bi;
  }
}

// ---------------- Wd = Wtop - Wbot ----------------
__global__ void k_wd(const float* __restrict__ W, float* __restrict__ Wd, int rows, int M){
  int t = blockIdx.x*256 + threadIdx.x;
  if (t < rows*M) Wd[t] = W[t] - W[rows*M + t];
}

// ---------------- generic tiled matmul: C = A(nxK) @ B(KxM) [+bias][relu] ----------------
__global__ __launch_bounds__(256)
void k_mm(const float* __restrict__ A, const float* __restrict__ B,
          const float* __restrict__ bias, float* __restrict__ Cout,
          int n, int Kd, int M, int relu){
  __shared__ float la[16][68], lb[16][68];
  int tid = threadIdx.x;
  int rb = blockIdx.y*64, cb = blockIdx.x*64;
  int lr = tid >> 2, lq = (tid & 3)*4;
  int ty = tid >> 4, tx = tid & 15;
  float acc[4][4] = {};
  for (int k0 = 0; k0 < Kd; k0 += 16){
    __syncthreads();
    #pragma unroll
    for (int u = 0; u < 4; u++){
      int k = k0 + lq + u;
      la[lq+u][lr] = (k < Kd) ? A[(size_t)(rb+lr)*Kd + k] : 0.f;
    }
    int kk = tid >> 4; int cc = (tid & 15)*4;
    #pragma unroll
    for (int u = 0; u < 4; u++){
      int c = cb + cc + u; int k = k0 + kk;
      lb[kk][cc+u] = (k < Kd && c < M) ? B[(size_t)k*M + c] : 0.f;
    }
    __syncthreads();
    #pragma unroll
    for (int k = 0; k < 16; k++){
      float4 a = *(const float4*)&la[k][ty*4];
      float4 b = *(const float4*)&lb[k][tx*4];
      float avv[4] = {a.x,a.y,a.z,a.w}, bvv[4] = {b.x,b.y,b.z,b.w};
      #pragma unroll
      for (int u = 0; u < 4; u++)
        #pragma unroll
        for (int v = 0; v < 4; v++) acc[u][v] += avv[u]*bvv[v];
    }
  }
  #pragma unroll
  for (int u = 0; u < 4; u++){
    int r = rb + ty*4 + u;
    #pragma unroll
    for (int v = 0; v < 4; v++){
      int c = cb + tx*4 + v;
      if (c < M){
        float x = acc[u][v] + (bias ? bias[c] : 0.f);
        if (relu) x = fmaxf(x, 0.f);
        Cout[(size_t)r*M + c] = x;
      }
    }
  }
}

// ---------------- stats over A[i]+P[j] per channel ----------------
template<int C>
__global__ __launch_bounds__(256)
void k_stats1(const float* __restrict__ A, const float* __restrict__ P,
              const int* __restrict__ idx, float* __restrict__ ssum, float* __restrict__ ssq){
  __shared__ int si[128], sj[128];
  int tid = threadIdx.x;
  int s0 = blockIdx.x*128;
  if (tid < 128){ si[tid] = (s0 + tid)/KNN; sj[tid] = idx[s0 + tid]; }
  __syncthreads();
  constexpr int MPAR = 256/C;
  int tc = tid % C, sr = tid / C;
  float s = 0.f, q = 0.f;
  for (int m = sr; m < 128; m += MPAR){
    float v = A[(size_t)si[m]*C + tc] + P[(size_t)sj[m]*C + tc];
    s += v; q += v*v;
  }
  if constexpr (MPAR > 1){
    __shared__ float rs[256], rq[256];
    rs[tid] = s; rq[tid] = q; __syncthreads();
    if (sr == 0){
      for (int u = 1; u < MPAR; u++){ s += rs[u*C + tc]; q += rq[u*C + tc]; }
    }
  }
  if (sr == 0){ atomicAdd(&ssum[tc], s); atomicAdd(&ssq[tc], q); }
}

// ---------------- column stats over dense X (rows = N*KNN) ----------------
template<int C>
__global__ __launch_bounds__(256)
void k_colstats(const float* __restrict__ X, float* __restrict__ ssum, float* __restrict__ ssq){
  constexpr int MPAR = 256/C;
  int tid = threadIdx.x;
  int tc = tid % C, sr = tid / C;
  int base = blockIdx.x*256;
  float s = 0.f, q = 0.f;
  for (int m = sr; m < 256; m += MPAR){
    float v = X[(size_t)(base + m)*C + tc];
    s += v; q += v*v;
  }
  if constexpr (MPAR > 1){
    __shared__ float rs[256], rq[256];
    rs[tid] = s; rq[tid] = q; __syncthreads();
    if (sr == 0){
      for (int u = 1; u < MPAR; u++){ s += rs[u*C + tc]; q += rq[u*C + tc]; }
    }
  }
  if (sr == 0){ atomicAdd(&ssum[tc], s); atomicAdd(&ssq[tc], q); }
}

__global__ void k_bn_final(const float* __restrict__ ssum, const float* __restrict__ ssq,
                           const float* __restrict__ g, const float* __restrict__ be,
                           float* __restrict__ sb, float* __restrict__ tb, int C, float invn){
  int c = threadIdx.x;
  if (c < C){
    float mu = ssum[c]*invn;
    float var = fmaxf(ssq[c]*invn - mu*mu, 0.f);
    float s = g[c]*rsqrtf(var + 1e-5f);
    sb[c] = s; tb[c] = be[c] - mu*s;
  }
}

// ---------------- per-edge matmul: out = relu(bn1(A[i]+P[j])) @ W + bias ----------------
template<int C>
__global__ __launch_bounds__(256)
void k_edge_mm(const float* __restrict__ A, const float* __restrict__ P,
               const int* __restrict__ idx, const float* __restrict__ sb,
               const float* __restrict__ tb, const float* __restrict__ W,
               const float* __restrict__ bias, float* __restrict__ out){
  constexpr int BM   = (C == 256) ? 32 : 64;
  constexpr int KT   = (C == 256) ? 16 : 64;
  constexpr int COLG = C/8;
  constexpr int ROWG = 256/COLG;
  constexpr int EPT  = BM/ROWG;
  constexpr int MPAR = 256/C;
  __shared__ float e2[BM][C+1];
  __shared__ float wt[KT][C+4];
  __shared__ int sj[BM];
  int tid = threadIdx.x;
  int s0 = blockIdx.x*BM;
  if (tid < BM) sj[tid] = idx[s0 + tid];
  __syncthreads();
  for (int mb = 0; mb < BM; mb += MPAR){
    int m = mb + tid / C;
    int c = tid % C;
    int i = (s0 + m)/KNN;
    int j = sj[m];
    float v = (A[(size_t)i*C + c] + P[(size_t)j*C + c])*sb[c] + tb[c];
    e2[m][c] = fmaxf(v, 0.f);
  }
  float acc[EPT][8];
  #pragma unroll
  for (int m = 0; m < EPT; m++)
    #pragma unroll
    for (int u = 0; u < 8; u++) acc[m][u] = 0.f;
  int tr = tid / COLG, tc = tid % COLG;
  for (int kt = 0; kt < C; kt += KT){
    __syncthreads();
    for (int t = tid; t < KT*C; t += 256){
      wt[t / C][t % C] = W[(size_t)(kt + t/C)*C + (t % C)];
    }
    __syncthreads();
    #pragma unroll 4
    for (int k = 0; k < KT; k++){
      float4 w0 = *(const float4*)&wt[k][tc*8];
      float4 w1 = *(const float4*)&wt[k][tc*8 + 4];
      float b[8] = {w0.x,w0.y,w0.z,w0.w,w1.x,w1.y,w1.z,w1.w};
      #pragma unroll
      for (int m = 0; m < EPT; m++){
        float a = e2[tr*EPT + m][kt + k];
        #pragma unroll
        for (int u = 0; u < 8; u++) acc[m][u] += a*b[u];
      }
    }
  }
  #pragma unroll
  for (int m = 0; m < EPT; m++){
    int row = s0 + tr*EPT + m;
    float4 o0, o1;
    o0.x = acc[m][0] + bias[tc*8+0]; o0.y = acc[m][1] + bias[tc*8+1];
    o0.z = acc[m][2] + bias[tc*8+2]; o0.w = acc[m][3] + bias[tc*8+3];
    o1.x = acc[m][4] + bias[tc*8+4]; o1.y = acc[m][5] + bias[tc*8+5];
    o1.z = acc[m][6] + bias[tc*8+6]; o1.w = acc[m][7] + bias[tc*8+7];
    *(float4*)&out[(size_t)row*C + tc*8]     = o0;
    *(float4*)&out[(size_t)row*C + tc*8 + 4] = o1;
  }
}

// ---------------- bn2 + relu + max over K ----------------
template<int C>
__global__ void k_maxpool(const float* __restrict__ X, const float* __restrict__ sb,
                          const float* __restrict__ tb, float* __restrict__ H){
  constexpr int NPB = 256/C;
  int node = blockIdx.x*NPB + threadIdx.x / C;
  int c = threadIdx.x % C;
  float s = sb[c], t = tb[c];
  float mx = 0.f;
  for (int k = 0; k < KNN; k++){
    float v = X[(size_t)(node*KNN + k)*C + c]*s + t;
    mx = fmaxf(mx, v);
  }
  H[(size_t)node*C + c] = mx;
}

// ---------------- gconv aggregation ----------------
template<int C>
__global__ void k_agg(const float* __restrict__ X, const int* __restrict__ roff,
                      const int* __restrict__ csr, const float* __restrict__ dout,
                      const float* __restrict__ din, float* __restrict__ XA){
  int i = blockIdx.x; int c = threadIdx.x;
  float acc = 0.f;
  int b = roff[i], e = roff[i+1];
  for (int t = b; t < e; t++){
    int s = csr[t];
    acc += X[(size_t)s*C + c]*dout[s];
  }
  XA[(size_t)i*C + c] = acc*din[i];
}

// ================= host =================
extern "C" void kernel_launch(void* const* d_in, const int* in_sizes, int n_in,
                              void* d_out, int out_size, void* d_ws, size_t ws_size,
                              hipStream_t stream){
  const float* feat = (const float*)d_in[0];
  const int*   src  = (const int*)d_in[1];
  const int*   dst  = (const int*)d_in[2];
  const float* Wc1  = (const float*)d_in[3];
  const float* bc1  = (const float*)d_in[4];
  const float* Wc2  = (const float*)d_in[5];
  const float* bc2  = (const float*)d_in[6];
  const float* Wc3  = (const float*)d_in[7];
  const float* bc3  = (const float*)d_in[8];
  const float* W11  = (const float*)d_in[9];
  const float* b11  = (const float*)d_in[10];
  const float* g11  = (const float*)d_in[11];
  const float* be11 = (const float*)d_in[12];
  const float* W12  = (const float*)d_in[13];
  const float* b12  = (const float*)d_in[14];
  const float* g12  = (const float*)d_in[15];
  const float* be12 = (const float*)d_in[16];
  const float* W21  = (const float*)d_in[17];
  const float* b21  = (const float*)d_in[18];
  const float* g21  = (const float*)d_in[19];
  const float* be21 = (const float*)d_in[20];
  const float* W22  = (const float*)d_in[21];
  const float* b22  = (const float*)d_in[22];
  const float* g22  = (const float*)d_in[23];
  const float* be22 = (const float*)d_in[24];
  float* out = (float*)d_out;

  char* w = (char*)d_ws; size_t off = 0;
  auto alloc = [&](size_t bytes)->void*{
    void* p = w + off;
    off += bytes; off = (off + 255) & ~(size_t)255;
    return p;
  };
  int* cnt_s  = (int*)alloc(NN*4);
  int* cnt_d  = (int*)alloc(NN*4);
  int* roff   = (int*)alloc((NN+1)*4);
  int* cursor = (int*)alloc(NN*4);
  int* csr    = (int*)alloc(NE*4);
  int* idx    = (int*)alloc((size_t)NN*KNN*4);
  float* dout = (float*)alloc(NN*4);
  float* din  = (float*)alloc(NN*4);
  float* sqv  = (float*)alloc(NN*4);
  float* h1   = (float*)alloc((size_t)NN*256*4);
  float* h2   = (float*)alloc((size_t)NN*256*4);
  float* h3   = (float*)alloc((size_t)NN*256*4);
  float* h4   = (float*)alloc((size_t)NN*64*4);
  float* xa   = (float*)alloc((size_t)NN*256*4);
  float* Abuf = (float*)alloc((size_t)NN*256*4);
  float* Pbuf = (float*)alloc((size_t)NN*256*4);
  float* Wd   = (float*)alloc(256*256*4);
  float* ssum = (float*)alloc(256*4);
  float* ssq  = (float*)alloc(256*4);
  float* sbn  = (float*)alloc(256*4);
  float* tbn  = (float*)alloc(256*4);
  float* out2 = (float*)alloc((size_t)NN*KNN*256*4);   // 167.8 MB
  // kNN scratch aliases out2 (consumed before edge_mm writes out2):
  float* pd = out2;                                           // 8192*320*4 = 10.5 MB
  int*   pi = (int*)(out2 + (size_t)NN*SPL*40);               // 10.5 MB
  unsigned short* xcat = (unsigned short*)((char*)pi + (size_t)NN*SPL*40*4);  // 8.4 MB
  (void)ws_size; (void)n_in; (void)in_sizes; (void)out_size;

  const float invn = 1.0f / (float)(NN*KNN);

  // graph prep
  k_zero_i<<<32, 256, 0, stream>>>(cnt_s, NN);
  k_zero_i<<<32, 256, 0, stream>>>(cnt_d, NN);
  k_zero_i<<<32, 256, 0, stream>>>(cursor, NN);
  k_count<<<NE/256, 256, 0, stream>>>(src, dst, cnt_s, cnt_d);
  k_deg<<<32, 256, 0, stream>>>(cnt_s, cnt_d, dout, din);
  k_scan<<<1, 256, 0, stream>>>(cnt_d, roff);
  k_fill<<<NE/256, 256, 0, stream>>>(src, dst, roff, cursor, csr);

  // gconv1 -> h1
  k_gconv1<<<NN/4, 256, 0, stream>>>(feat, roff, csr, dout, din, Wc1, bc1, h1);

  // ---- edge conv 1 (input h1, 256 -> 256 -> 256) ----
  k_sq<<<NN/4, 256, 0, stream>>>(h1, sqv);
  k_split<<<NN, 256, 0, stream>>>(h1, xcat);
  k_gramtopk<<<dim3(SPL, NN/GBM), 256, 0, stream>>>(xcat, sqv, pd, pi);
  k_knn_merge<<<NN/4, 256, 0, stream>>>(pd, pi, idx);
  k_wd<<<256, 256, 0, stream>>>(W11, Wd, 256, 256);
  k_mm<<<dim3(4, NN/64), 256, 0, stream>>>(h1, Wd, b11, Abuf, NN, 256, 256, 0);
  k_mm<<<dim3(4, NN/64), 256, 0, stream>>>(h1, W11 + 256*256, nullptr, Pbuf, NN, 256, 256, 0);
  k_zero<<<2, 256, 0, stream>>>(ssum, 256); k_zero<<<2, 256, 0, stream>>>(ssq, 256);
  k_stats1<256><<<NN*KNN/128, 256, 0, stream>>>(Abuf, Pbuf, idx, ssum, ssq);
  k_bn_final<<<1, 256, 0, stream>>>(ssum, ssq, g11, be11, sbn, tbn, 256, invn);
  k_edge_mm<256><<<NN*KNN/32, 256, 0, stream>>>(Abuf, Pbuf, idx, sbn, tbn, W12, b12, out2);
  k_zero<<<2, 256, 0, stream>>>(ssum, 256); k_zero<<<2, 256, 0, stream>>>(ssq, 256);
  k_colstats<256><<<NN*KNN/256, 256, 0, stream>>>(out2, ssum, ssq);
  k_bn_final<<<1, 256, 0, stream>>>(ssum, ssq, g12, be12, sbn, tbn, 256, invn);
  k_maxpool<256><<<NN, 256, 0, stream>>>(out2, sbn, tbn, h2);

  // gconv2 -> h3
  k_agg<256><<<NN, 256, 0, stream>>>(h2, roff, csr, dout, din, xa);
  k_mm<<<dim3(4, NN/64), 256, 0, stream>>>(xa, Wc2, bc2, h3, NN, 256, 256, 1);

  // ---- edge conv 2 (input h3, 256 -> 64 -> 64) ----
  k_sq<<<NN/4, 256, 0, stream>>>(h3, sqv);
  k_split<<<NN, 256, 0, stream>>>(h3, xcat);
  k_gramtopk<<<dim3(SPL, NN/GBM), 256, 0, stream>>>(xcat, sqv, pd, pi);
  k_knn_merge<<<NN/4, 256, 0, stream>>>(pd, pi, idx);
  k_wd<<<64, 256, 0, stream>>>(W21, Wd, 256, 64);
  k_mm<<<dim3(1, NN/64), 256, 0, stream>>>(h3, Wd, b21, Abuf, NN, 256, 64, 0);
  k_mm<<<dim3(1, NN/64), 256, 0, stream>>>(h3, W21 + 256*64, nullptr, Pbuf, NN, 256, 64, 0);
  k_zero<<<2, 256, 0, stream>>>(ssum, 256); k_zero<<<2, 256, 0, stream>>>(ssq, 256);
  k_stats1<64><<<NN*KNN/128, 256, 0, stream>>>(Abuf, Pbuf, idx, ssum, ssq);
  k_bn_final<<<1, 256, 0, stream>>>(ssum, ssq, g21, be21, sbn, tbn, 64, invn);
  k_edge_mm<64><<<NN*KNN/64, 256, 0, stream>>>(Abuf, Pbuf, idx, sbn, tbn, W22, b22, out2);
  k_zero<<<2, 256, 0, stream>>>(ssum, 256); k_zero<<<2, 256, 0, stream>>>(ssq, 256);
  k_colstats<64><<<NN*KNN/256, 256, 0, stream>>>(out2, ssum, ssq);
  k_bn_final<<<1, 256, 0, stream>>>(ssum, ssq, g22, be22, sbn, tbn, 64, invn);
  k_maxpool<64><<<NN/4, 256, 0, stream>>>(out2, sbn, tbn, h4);

  // gconv3 -> out
  k_agg<64><<<NN, 64, 0, stream>>>(h4, roff, csr, dout, din, xa);
  k_mm<<<dim3(1, NN/64), 256, 0, stream>>>(xa, Wc3, bc3, out, NN, 64, 32, 0);
}

// Round 6
// 4301.823 us; speedup vs baseline: 2.3035x; 1.0408x over previous
//
#include <hip/hip_runtime.h>

#define NN 8192
#define NE 131072
#define KNN 20
#define SPL 8            // kNN column splits (x-dim => XCD pinning)
#define CPS (NN/SPL)     // 1024 cols per split
#define GT_RPB 32        // gramtopk rows per block

typedef __attribute__((ext_vector_type(4))) float f32x4;
typedef __attribute__((ext_vector_type(8))) __bf16 bf16x8;

// ---------------- utility ----------------
__global__ void k_zero(float* p, int n){
  int i = blockIdx.x*256 + threadIdx.x;
  if (i < n) p[i] = 0.f;
}
__global__ void k_zero_i(int* p, int n){
  int i = blockIdx.x*256 + threadIdx.x;
  if (i < n) p[i] = 0;
}

__device__ __forceinline__ unsigned short f2bf(float x){
  unsigned u = __float_as_uint(x);
  unsigned r = (u + 0x7fff + ((u >> 16) & 1)) >> 16;
  return (unsigned short)r;
}
__device__ __forceinline__ float bf2f(unsigned short h){
  return __uint_as_float((unsigned)h << 16);
}
__device__ __forceinline__ void gload16(const void* g, void* l){
  __builtin_amdgcn_global_load_lds(
      (const __attribute__((address_space(1))) void*)g,
      (__attribute__((address_space(3))) void*)l, 16, 0, 0);
}

// ---------------- graph prep ----------------
__global__ void k_count(const int* __restrict__ src, const int* __restrict__ dst,
                        int* cs, int* cd){
  int e = blockIdx.x*256 + threadIdx.x;
  if (e < NE){ atomicAdd(&cs[src[e]], 1); atomicAdd(&cd[dst[e]], 1); }
}
__global__ void k_deg(const int* cs, const int* cd, float* dout, float* din){
  int i = blockIdx.x*256 + threadIdx.x;
  if (i < NN){
    dout[i] = rsqrtf((float)max(cs[i], 1));
    din[i]  = rsqrtf((float)max(cd[i], 1));
  }
}
__global__ void k_scan(const int* __restrict__ cnt, int* __restrict__ off){
  __shared__ int sh[256];
  __shared__ int carry;
  int tid = threadIdx.x;
  if (tid == 0) carry = 0;
  __syncthreads();
  for (int base = 0; base < NN; base += 256){
    int v = cnt[base + tid];
    int x = v;
    sh[tid] = x; __syncthreads();
    for (int o = 1; o < 256; o <<= 1){
      int y = (tid >= o) ? sh[tid - o] : 0;
      __syncthreads();
      x += y; sh[tid] = x;
      __syncthreads();
    }
    off[base + tid] = carry + x - v;
    __syncthreads();
    if (tid == 255){
      carry += x;
      if (base + 256 == NN) off[NN] = carry;
    }
    __syncthreads();
  }
}
__global__ void k_fill(const int* __restrict__ src, const int* __restrict__ dst,
                       const int* __restrict__ roff, int* cursor, int* csr){
  int e = blockIdx.x*256 + threadIdx.x;
  if (e < NE){
    int d = dst[e];
    int p = atomicAdd(&cursor[d], 1);
    csr[roff[d] + p] = src[e];
  }
}

// ---------------- gconv1 fused (3 -> 256) ----------------
__global__ void k_gconv1(const float* __restrict__ feat, const int* __restrict__ roff,
                         const int* __restrict__ csr, const float* __restrict__ dout,
                         const float* __restrict__ din, const float* __restrict__ Wc1,
                         const float* __restrict__ bc1, float* __restrict__ h1){
  int wid = threadIdx.x >> 6, lane = threadIdx.x & 63;
  int i = blockIdx.x*4 + wid;
  float a0=0.f, a1=0.f, a2=0.f;
  int beg = roff[i], end = roff[i+1];
  for (int t = beg + lane; t < end; t += 64){
    int s = csr[t]; float w = dout[s];
    a0 += feat[s*3+0]*w; a1 += feat[s*3+1]*w; a2 += feat[s*3+2]*w;
  }
  for (int m = 32; m; m >>= 1){
    a0 += __shfl_xor(a0, m); a1 += __shfl_xor(a1, m); a2 += __shfl_xor(a2, m);
  }
  float dn = din[i];
  a0 *= dn; a1 *= dn; a2 *= dn;
  for (int c = lane; c < 256; c += 64){
    float r = a0*Wc1[c] + a1*Wc1[256+c] + a2*Wc1[512+c] + bc1[c];
    h1[(size_t)i*256 + c] = fmaxf(r, 0.f);
  }
}

// ---------------- row squared norms (C=256) ----------------
__global__ void k_sq(const float* __restrict__ X, float* __restrict__ sq){
  int wid = threadIdx.x >> 6, lane = threadIdx.x & 63;
  int i = blockIdx.x*4 + wid;
  float4 v = *(const float4*)&X[(size_t)i*256 + lane*4];
  float s = v.x*v.x + v.y*v.y + v.z*v.z + v.w*v.w;
  for (int m = 32; m; m >>= 1) s += __shfl_xor(s, m);
  if (lane == 0) sq[i] = s;
}

// ---------------- split f32 -> [hi|lo] bf16, Xcat[n][512] ----------------
__global__ void k_split(const float* __restrict__ X, unsigned short* __restrict__ xcat){
  int row = blockIdx.x, c = threadIdx.x;
  float x = X[(size_t)row*256 + c];
  unsigned short h = f2bf(x);
  unsigned short lo = f2bf(x - bf2f(h));
  xcat[(size_t)row*512 + c] = h;
  xcat[(size_t)row*512 + 256 + c] = lo;
}

// ---------------- FUSED gram + top-K partial selection (v2) ----------------
// Block: 32 rows x one 1024-col split. A ([hi|lo], 32 KB) staged ONCE into
// padded LDS (1040 B/row); per 128-col tile only B sections are staged.
// MFMA split-bf16 K=768: sections A{hi,lo,hi} x B{hi,hi,lo}. Keys go to an LDS
// tile; lane owns (row, 16-col slice) -> private sorted top-20 of its 128
// candidates (exact: any true row-top-20 elem survives its subset's top-20);
// 8-lane shfl merge -> one sorted 20-list per (row, split).
__global__ __launch_bounds__(256, 2)
void k_gramtopk(const unsigned short* __restrict__ Xcat, const float* __restrict__ sq,
                float* __restrict__ pd, int* __restrict__ pi){
  __shared__ unsigned short Alds[GT_RPB*520];  // 520 shorts = 1040 B/row (64 granules + pad)
  __shared__ unsigned short sB[128*64];        // 16 KB per section stage
  __shared__ float tile[GT_RPB][132];          // 16.9 KB keys
  __shared__ float sqr[GT_RPB];
  __shared__ float sqc[128];

  int tid = threadIdx.x;
  int lw = tid >> 6, l = tid & 63;
  int split = blockIdx.x;          // x fastest => bid%8 = split => XCD pinning
  int rb = blockIdx.y*GT_RPB;
  int cb0 = split*CPS;

  if (tid < GT_RPB) sqr[tid] = sq[rb + tid];

  // ---- stage A once: 32 rows x 65 granules (64 data + 1 pad) ----
  #pragma unroll 1
  for (int rnd = 0; rnd < 9; rnd++){
    int g = rnd*256 + tid;
    if (g < GT_RPB*65){
      int row = g/65;
      int colg = g - row*65;
      int cg = (colg == 64) ? 0 : colg;   // pad granule: harmless duplicate
      gload16(Xcat + (size_t)(rb + row)*512 + cg*8,
              (char*)Alds + ((size_t)(rnd*256 + lw*64))*16);
    }
  }

  // B staging constants: per gload a wave writes 1KB = 8 rows x 8 swizzled granules
  int srow = l >> 3;
  int scol = (l & 7) ^ srow;
  const unsigned short* srcB[4];
  char* dstB[4];
  #pragma unroll
  for (int i = 0; i < 4; i++){
    int c = lw*4 + i;              // 0..15
    int row = c*8 + srow;          // 0..127
    srcB[i] = Xcat + (size_t)(cb0 + row)*512 + scol*8;
    dstB[i] = (char*)sB + c*1024;
  }

  // fragment geometry: 4 waves = 2(m) x 2(n); wave does 16 rows x 64 cols
  int wm = lw >> 1, wn = lw & 1;
  int fm = l & 15, kg = l >> 4;
  int rowa = wm*16 + fm;           // A row 0..31
  unsigned offB[4][2];
  #pragma unroll
  for (int nf = 0; nf < 4; nf++){
    int rowb = wn*64 + nf*16 + fm;
    #pragma unroll
    for (int ks = 0; ks < 2; ks++)
      offB[nf][ks] = rowb*128 + (((unsigned)(ks*4 + kg) ^ (rowb & 7)))*16;
  }

  // per-lane topk state: lane owns (row = tid>>3, slice = tid&7 -> 16 cols)
  int myrow = tid >> 3, slice = tid & 7;
  float kd[KNN]; int ki[KNN];
  #pragma unroll
  for (int u = 0; u < KNN; u++){ kd[u] = INFINITY; ki[u] = 0x7fffffff; }

  __syncthreads();   // A resident (drains vmcnt)

  #pragma unroll 1
  for (int ct = 0; ct < CPS/128; ct++){
    if (tid < 128) sqc[tid] = sq[cb0 + ct*128 + tid];

    f32x4 acc[4];
    #pragma unroll
    for (int n = 0; n < 4; n++) acc[n] = (f32x4){0.f,0.f,0.f,0.f};

    #pragma unroll 1
    for (int s = 0; s < 12; s++){
      int sec = s >> 2;
      int cbB = (sec == 2 ? 256 : 0) + (s & 3)*64;   // shorts
      int gkA = (sec == 1 ? 32 : 0) + (s & 3)*8;     // granule base in A row
      #pragma unroll
      for (int i = 0; i < 4; i++) gload16(srcB[i] + cbB, dstB[i]);
      __syncthreads();
      #pragma unroll
      for (int ks = 0; ks < 2; ks++){
        bf16x8 a = *(const bf16x8*)((const char*)Alds + rowa*1040 + (gkA + ks*4 + kg)*16);
        #pragma unroll
        for (int nf = 0; nf < 4; nf++){
          bf16x8 b = *(const bf16x8*)((const char*)sB + offB[nf][ks]);
          acc[nf] = __builtin_amdgcn_mfma_f32_16x16x32_bf16(a, b, acc[nf], 0, 0, 0);
        }
      }
      __syncthreads();
    }
    #pragma unroll
    for (int i = 0; i < 4; i++) srcB[i] += 128*512;   // next 128 B-rows

    // epilogue: keys into tile. C/D: col = lane&15, row = (lane>>4)*4 + reg
    #pragma unroll
    for (int nf = 0; nf < 4; nf++){
      int ocol = wn*64 + nf*16 + fm;
      float sc = sqc[ocol];
      #pragma unroll
      for (int r = 0; r < 4; r++){
        int orow = wm*16 + kg*4 + r;
        tile[orow][ocol] = (sqr[orow] + sc) - 2.f*acc[nf][r];
      }
    }
    __syncthreads();

    // scan: 4 steps x 4 keys from own slice (rolled — I-cache)
    int jb0 = cb0 + ct*128 + slice*16;
    #pragma unroll 1
    for (int st = 0; st < 4; st++){
      float4 kv = *(const float4*)&tile[myrow][slice*16 + st*4];
      float ke0 = kv.x, ke1 = kv.y, ke2 = kv.z, ke3 = kv.w;
      int jb = jb0 + st*4;
      int done = 0;
      float m = INFINITY; int sel = -1;
      {
        float t19 = kd[KNN-1];
        if (ke0 < t19 && ke0 < m){ m = ke0; sel = 0; }
        if (ke1 < t19 && ke1 < m){ m = ke1; sel = 1; }
        if (ke2 < t19 && ke2 < m){ m = ke2; sel = 2; }
        if (ke3 < t19 && ke3 < m){ m = ke3; sel = 3; }
      }
      while (__any(sel >= 0)){
        if (sel >= 0){
          float nk = m; int ni = jb + sel;
          #pragma unroll
          for (int u = 0; u < KNN; u++){
            bool sw = nk < kd[u];
            float tv = kd[u]; int ti = ki[u];
            if (sw){ kd[u] = nk; ki[u] = ni; nk = tv; ni = ti; }
          }
          done |= (1 << sel);
        }
        m = INFINITY; sel = -1;
        {
          float t19 = kd[KNN-1];
          if (!(done & 1) && ke0 < t19 && ke0 < m){ m = ke0; sel = 0; }
          if (!(done & 2) && ke1 < t19 && ke1 < m){ m = ke1; sel = 1; }
          if (!(done & 4) && ke2 < t19 && ke2 < m){ m = ke2; sel = 2; }
          if (!(done & 8) && ke3 < t19 && ke3 < m){ m = ke3; sel = 3; }
        }
      }
    }
    __syncthreads();
  }

  // 8-lane (slice-group) merge: pop global min 20x -> sorted list per (row,split)
  size_t base = ((size_t)(rb + myrow)*SPL + split)*20;
  #pragma unroll 1
  for (int r = 0; r < KNN; r++){
    float bv = kd[0]; int bi = ki[0];
    #pragma unroll
    for (int m = 1; m <= 4; m <<= 1){
      float ov = __shfl_xor(bv, m); int oi = __shfl_xor(bi, m);
      if (ov < bv || (ov == bv && oi < bi)){ bv = ov; bi = oi; }
    }
    if (ki[0] == bi){   // winner (col idx unique)
      #pragma unroll
      for (int u = 0; u < KNN-1; u++){ kd[u] = kd[u+1]; ki[u] = ki[u+1]; }
      kd[KNN-1] = INFINITY; ki[KNN-1] = 0x7fffffff;
    }
    if (slice == 0){ pd[base + r] = bv; pi[base + r] = bi; }
  }
}

// ---------------- merge 8 sorted 20-lists/row -> exact top-20 ----------------
__global__ __launch_bounds__(256)
void k_knn_merge(const float* __restrict__ pd, const int* __restrict__ pi,
                 int* __restrict__ idxo){
  int tid = threadIdx.x, lw = tid >> 6, l = tid & 63;
  int row = blockIdx.x*4 + lw;
  float v0, v1, v2, v3, v4; int i0, i1, i2, i3, i4;
  if (l < 32){
    size_t base = (size_t)row*(SPL*20) + (l >> 2)*20 + (l & 3)*5;  // sorted chunk
    v0 = pd[base+0]; v1 = pd[base+1]; v2 = pd[base+2]; v3 = pd[base+3]; v4 = pd[base+4];
    i0 = pi[base+0]; i1 = pi[base+1]; i2 = pi[base+2]; i3 = pi[base+3]; i4 = pi[base+4];
  } else {
    v0 = v1 = v2 = v3 = v4 = INFINITY;
    i0 = i1 = i2 = i3 = i4 = 0x7fffffff;
  }
  #pragma unroll 1
  for (int r = 0; r < KNN; r++){
    float bv = v0; int bi = i0;
    #pragma unroll
    for (int mm = 32; mm; mm >>= 1){
      float ov = __shfl_xor(bv, mm); int oi = __shfl_xor(bi, mm);
      if (ov < bv || (ov == bv && oi < bi)){ bv = ov; bi = oi; }
    }
    if (i0 == bi){ v0=v1;i0=i1; v1=v2;i1=i2; v2=v3;i2=i3; v3=v4;i3=i4; v4=INFINITY; i4=0x7fffffff; }
    if (l == 0) idxo[(size_t)row*KNN + r] = bi;
  }
}

// ---------------- Wd = Wtop - Wbot ----------------
__global__ void k_wd(const float* __restrict__ W, float* __restrict__ Wd, int rows, int M){
  int t = blockIdx.x*256 + threadIdx.x;
  if (t < rows*M) Wd[t] = W[t] - W[rows*M + t];
}

// ---------------- generic tiled matmul: C = A(nxK) @ B(KxM) [+bias][relu] ----------------
__global__ __launch_bounds__(256)
void k_mm(const float* __restrict__ A, const float* __restrict__ B,
          const float* __restrict__ bias, float* __restrict__ Cout,
          int n, int Kd, int M, int relu){
  __shared__ float la[16][68], lb[16][68];
  int tid = threadIdx.x;
  int rb = blockIdx.y*64, cb = blockIdx.x*64;
  int lr = tid >> 2, lq = (tid & 3)*4;
  int ty = tid >> 4, tx = tid & 15;
  float acc[4][4] = {};
  for (int k0 = 0; k0 < Kd; k0 += 16){
    __syncthreads();
    #pragma unroll
    for (int u = 0; u < 4; u++){
      int k = k0 + lq + u;
      la[lq+u][lr] = (k < Kd) ? A[(size_t)(rb+lr)*Kd + k] : 0.f;
    }
    int kk = tid >> 4; int cc = (tid & 15)*4;
    #pragma unroll
    for (int u = 0; u < 4; u++){
      int c = cb + cc + u; int k = k0 + kk;
      lb[kk][cc+u] = (k < Kd && c < M) ? B[(size_t)k*M + c] : 0.f;
    }
    __syncthreads();
    #pragma unroll
    for (int k = 0; k < 16; k++){
      float4 a = *(const float4*)&la[k][ty*4];
      float4 b = *(const float4*)&lb[k][tx*4];
      float avv[4] = {a.x,a.y,a.z,a.w}, bvv[4] = {b.x,b.y,b.z,b.w};
      #pragma unroll
      for (int u = 0; u < 4; u++)
        #pragma unroll
        for (int v = 0; v < 4; v++) acc[u][v] += avv[u]*bvv[v];
    }
  }
  #pragma unroll
  for (int u = 0; u < 4; u++){
    int r = rb + ty*4 + u;
    #pragma unroll
    for (int v = 0; v < 4; v++){
      int c = cb + tx*4 + v;
      if (c < M){
        float x = acc[u][v] + (bias ? bias[c] : 0.f);
        if (relu) x = fmaxf(x, 0.f);
        Cout[(size_t)r*M + c] = x;
      }
    }
  }
}

// ---------------- stats over A[i]+P[j] per channel ----------------
template<int C>
__global__ __launch_bounds__(256)
void k_stats1(const float* __restrict__ A, const float* __restrict__ P,
              const int* __restrict__ idx, float* __restrict__ ssum, float* __restrict__ ssq){
  __shared__ int si[128], sj[128];
  int tid = threadIdx.x;
  int s0 = blockIdx.x*128;
  if (tid < 128){ si[tid] = (s0 + tid)/KNN; sj[tid] = idx[s0 + tid]; }
  __syncthreads();
  constexpr int MPAR = 256/C;
  int tc = tid % C, sr = tid / C;
  float s = 0.f, q = 0.f;
  for (int m = sr; m < 128; m += MPAR){
    float v = A[(size_t)si[m]*C + tc] + P[(size_t)sj[m]*C + tc];
    s += v; q += v*v;
  }
  if constexpr (MPAR > 1){
    __shared__ float rs[256], rq[256];
    rs[tid] = s; rq[tid] = q; __syncthreads();
    if (sr == 0){
      for (int u = 1; u < MPAR; u++){ s += rs[u*C + tc]; q += rq[u*C + tc]; }
    }
  }
  if (sr == 0){ atomicAdd(&ssum[tc], s); atomicAdd(&ssq[tc], q); }
}

// ---------------- column stats over dense X (rows = N*KNN) ----------------
template<int C>
__global__ __launch_bounds__(256)
void k_colstats(const float* __restrict__ X, float* __restrict__ ssum, float* __restrict__ ssq){
  constexpr int MPAR = 256/C;
  int tid = threadIdx.x;
  int tc = tid % C, sr = tid / C;
  int base = blockIdx.x*256;
  float s = 0.f, q = 0.f;
  for (int m = sr; m < 256; m += MPAR){
    float v = X[(size_t)(base + m)*C + tc];
    s += v; q += v*v;
  }
  if constexpr (MPAR > 1){
    __shared__ float rs[256], rq[256];
    rs[tid] = s; rq[tid] = q; __syncthreads();
    if (sr == 0){
      for (int u = 1; u < MPAR; u++){ s += rs[u*C + tc]; q += rq[u*C + tc]; }
    }
  }
  if (sr == 0){ atomicAdd(&ssum[tc], s); atomicAdd(&ssq[tc], q); }
}

__global__ void k_bn_final(const float* __restrict__ ssum, const float* __restrict__ ssq,
                           const float* __restrict__ g, const float* __restrict__ be,
                           float* __restrict__ sb, float* __restrict__ tb, int C, float invn){
  int c = threadIdx.x;
  if (c < C){
    float mu = ssum[c]*invn;
    float var = fmaxf(ssq[c]*invn - mu*mu, 0.f);
    float s = g[c]*rsqrtf(var + 1e-5f);
    sb[c] = s; tb[c] = be[c] - mu*s;
  }
}

// ---------------- per-edge matmul: out = relu(bn1(A[i]+P[j])) @ W + bias ----------------
template<int C>
__global__ __launch_bounds__(256)
void k_edge_mm(const float* __restrict__ A, const float* __restrict__ P,
               const int* __restrict__ idx, const float* __restrict__ sb,
               const float* __restrict__ tb, const float* __restrict__ W,
               const float* __restrict__ bias, float* __restrict__ out){
  constexpr int BM   = (C == 256) ? 32 : 64;
  constexpr int KT   = (C == 256) ? 16 : 64;
  constexpr int COLG = C/8;
  constexpr int ROWG = 256/COLG;
  constexpr int EPT  = BM/ROWG;
  constexpr int MPAR = 256/C;
  __shared__ float e2[BM][C+1];
  __shared__ float wt[KT][C+4];
  __shared__ int sj[BM];
  int tid = threadIdx.x;
  int s0 = blockIdx.x*BM;
  if (tid < BM) sj[tid] = idx[s0 + tid];
  __syncthreads();
  for (int mb = 0; mb < BM; mb += MPAR){
    int m = mb + tid / C;
    int c = tid % C;
    int i = (s0 + m)/KNN;
    int j = sj[m];
    float v = (A[(size_t)i*C + c] + P[(size_t)j*C + c])*sb[c] + tb[c];
    e2[m][c] = fmaxf(v, 0.f);
  }
  float acc[EPT][8];
  #pragma unroll
  for (int m = 0; m < EPT; m++)
    #pragma unroll
    for (int u = 0; u < 8; u++) acc[m][u] = 0.f;
  int tr = tid / COLG, tc = tid % COLG;
  for (int kt = 0; kt < C; kt += KT){
    __syncthreads();
    for (int t = tid; t < KT*C; t += 256){
      wt[t / C][t % C] = W[(size_t)(kt + t/C)*C + (t % C)];
    }
    __syncthreads();
    #pragma unroll 4
    for (int k = 0; k < KT; k++){
      float4 w0 = *(const float4*)&wt[k][tc*8];
      float4 w1 = *(const float4*)&wt[k][tc*8 + 4];
      float b[8] = {w0.x,w0.y,w0.z,w0.w,w1.x,w1.y,w1.z,w1.w};
      #pragma unroll
      for (int m = 0; m < EPT; m++){
        float a = e2[tr*EPT + m][kt + k];
        #pragma unroll
        for (int u = 0; u < 8; u++) acc[m][u] += a*b[u];
      }
    }
  }
  #pragma unroll
  for (int m = 0; m < EPT; m++){
    int row = s0 + tr*EPT + m;
    float4 o0, o1;
    o0.x = acc[m][0] + bias[tc*8+0]; o0.y = acc[m][1] + bias[tc*8+1];
    o0.z = acc[m][2] + bias[tc*8+2]; o0.w = acc[m][3] + bias[tc*8+3];
    o1.x = acc[m][4] + bias[tc*8+4]; o1.y = acc[m][5] + bias[tc*8+5];
    o1.z = acc[m][6] + bias[tc*8+6]; o1.w = acc[m][7] + bias[tc*8+7];
    *(float4*)&out[(size_t)row*C + tc*8]     = o0;
    *(float4*)&out[(size_t)row*C + tc*8 + 4] = o1;
  }
}

// ---------------- bn2 + relu + max over K ----------------
template<int C>
__global__ void k_maxpool(const float* __restrict__ X, const float* __restrict__ sb,
                          const float* __restrict__ tb, float* __restrict__ H){
  constexpr int NPB = 256/C;
  int node = blockIdx.x*NPB + threadIdx.x / C;
  int c = threadIdx.x % C;
  float s = sb[c], t = tb[c];
  float mx = 0.f;
  for (int k = 0; k < KNN; k++){
    float v = X[(size_t)(node*KNN + k)*C + c]*s + t;
    mx = fmaxf(mx, v);
  }
  H[(size_t)node*C + c] = mx;
}

// ---------------- gconv aggregation ----------------
template<int C>
__global__ void k_agg(const float* __restrict__ X, const int* __restrict__ roff,
                      const int* __restrict__ csr, const float* __restrict__ dout,
                      const float* __restrict__ din, float* __restrict__ XA){
  int i = blockIdx.x; int c = threadIdx.x;
  float acc = 0.f;
  int b = roff[i], e = roff[i+1];
  for (int t = b; t < e; t++){
    int s = csr[t];
    acc += X[(size_t)s*C + c]*dout[s];
  }
  XA[(size_t)i*C + c] = acc*din[i];
}

// ================= host =================
extern "C" void kernel_launch(void* const* d_in, const int* in_sizes, int n_in,
                              void* d_out, int out_size, void* d_ws, size_t ws_size,
                              hipStream_t stream){
  const float* feat = (const float*)d_in[0];
  const int*   src  = (const int*)d_in[1];
  const int*   dst  = (const int*)d_in[2];
  const float* Wc1  = (const float*)d_in[3];
  const float* bc1  = (const float*)d_in[4];
  const float* Wc2  = (const float*)d_in[5];
  const float* bc2  = (const float*)d_in[6];
  const float* Wc3  = (const float*)d_in[7];
  const float* bc3  = (const float*)d_in[8];
  const float* W11  = (const float*)d_in[9];
  const float* b11  = (const float*)d_in[10];
  const float* g11  = (const float*)d_in[11];
  const float* be11 = (const float*)d_in[12];
  const float* W12  = (const float*)d_in[13];
  const float* b12  = (const float*)d_in[14];
  const float* g12  = (const float*)d_in[15];
  const float* be12 = (const float*)d_in[16];
  const float* W21  = (const float*)d_in[17];
  const float* b21  = (const float*)d_in[18];
  const float* g21  = (const float*)d_in[19];
  const float* be21 = (const float*)d_in[20];
  const float* W22  = (const float*)d_in[21];
  const float* b22  = (const float*)d_in[22];
  const float* g22  = (const float*)d_in[23];
  const float* be22 = (const float*)d_in[24];
  float* out = (float*)d_out;

  char* w = (char*)d_ws; size_t off = 0;
  auto alloc = [&](size_t bytes)->void*{
    void* p = w + off;
    off += bytes; off = (off + 255) & ~(size_t)255;
    return p;
  };
  int* cnt_s  = (int*)alloc(NN*4);
  int* cnt_d  = (int*)alloc(NN*4);
  int* roff   = (int*)alloc((NN+1)*4);
  int* cursor = (int*)alloc(NN*4);
  int* csr    = (int*)alloc(NE*4);
  int* idx    = (int*)alloc((size_t)NN*KNN*4);
  float* dout = (float*)alloc(NN*4);
  float* din  = (float*)alloc(NN*4);
  float* sqv  = (float*)alloc(NN*4);
  float* h1   = (float*)alloc((size_t)NN*256*4);
  float* h2   = (float*)alloc((size_t)NN*256*4);
  float* h3   = (float*)alloc((size_t)NN*256*4);
  float* h4   = (float*)alloc((size_t)NN*64*4);
  float* xa   = (float*)alloc((size_t)NN*256*4);
  float* Abuf = (float*)alloc((size_t)NN*256*4);
  float* Pbuf = (float*)alloc((size_t)NN*256*4);
  float* Wd   = (float*)alloc(256*256*4);
  float* ssum = (float*)alloc(256*4);
  float* ssq  = (float*)alloc(256*4);
  float* sbn  = (float*)alloc(256*4);
  float* tbn  = (float*)alloc(256*4);
  float* out2 = (float*)alloc((size_t)NN*KNN*256*4);   // 167.8 MB
  // kNN scratch aliases out2 (consumed before edge_mm writes out2):
  float* pd = out2;                                           // NN*SPL*20*4 = 5.24 MB
  int*   pi = (int*)(out2 + (size_t)NN*SPL*20);               // 5.24 MB
  unsigned short* xcat = (unsigned short*)((char*)pi + (size_t)NN*SPL*20*4);  // 8.4 MB
  (void)ws_size; (void)n_in; (void)in_sizes; (void)out_size;

  const float invn = 1.0f / (float)(NN*KNN);

  // graph prep
  k_zero_i<<<32, 256, 0, stream>>>(cnt_s, NN);
  k_zero_i<<<32, 256, 0, stream>>>(cnt_d, NN);
  k_zero_i<<<32, 256, 0, stream>>>(cursor, NN);
  k_count<<<NE/256, 256, 0, stream>>>(src, dst, cnt_s, cnt_d);
  k_deg<<<32, 256, 0, stream>>>(cnt_s, cnt_d, dout, din);
  k_scan<<<1, 256, 0, stream>>>(cnt_d, roff);
  k_fill<<<NE/256, 256, 0, stream>>>(src, dst, roff, cursor, csr);

  // gconv1 -> h1
  k_gconv1<<<NN/4, 256, 0, stream>>>(feat, roff, csr, dout, din, Wc1, bc1, h1);

  // ---- edge conv 1 (input h1, 256 -> 256 -> 256) ----
  k_sq<<<NN/4, 256, 0, stream>>>(h1, sqv);
  k_split<<<NN, 256, 0, stream>>>(h1, xcat);
  k_gramtopk<<<dim3(SPL, NN/GT_RPB), 256, 0, stream>>>(xcat, sqv, pd, pi);
  k_knn_merge<<<NN/4, 256, 0, stream>>>(pd, pi, idx);
  k_wd<<<256, 256, 0, stream>>>(W11, Wd, 256, 256);
  k_mm<<<dim3(4, NN/64), 256, 0, stream>>>(h1, Wd, b11, Abuf, NN, 256, 256, 0);
  k_mm<<<dim3(4, NN/64), 256, 0, stream>>>(h1, W11 + 256*256, nullptr, Pbuf, NN, 256, 256, 0);
  k_zero<<<2, 256, 0, stream>>>(ssum, 256); k_zero<<<2, 256, 0, stream>>>(ssq, 256);
  k_stats1<256><<<NN*KNN/128, 256, 0, stream>>>(Abuf, Pbuf, idx, ssum, ssq);
  k_bn_final<<<1, 256, 0, stream>>>(ssum, ssq, g11, be11, sbn, tbn, 256, invn);
  k_edge_mm<256><<<NN*KNN/32, 256, 0, stream>>>(Abuf, Pbuf, idx, sbn, tbn, W12, b12, out2);
  k_zero<<<2, 256, 0, stream>>>(ssum, 256); k_zero<<<2, 256, 0, stream>>>(ssq, 256);
  k_colstats<256><<<NN*KNN/256, 256, 0, stream>>>(out2, ssum, ssq);
  k_bn_final<<<1, 256, 0, stream>>>(ssum, ssq, g12, be12, sbn, tbn, 256, invn);
  k_maxpool<256><<<NN, 256, 0, stream>>>(out2, sbn, tbn, h2);

  // gconv2 -> h3
  k_agg<256><<<NN, 256, 0, stream>>>(h2, roff, csr, dout, din, xa);
  k_mm<<<dim3(4, NN/64), 256, 0, stream>>>(xa, Wc2, bc2, h3, NN, 256, 256, 1);

  // ---- edge conv 2 (input h3, 256 -> 64 -> 64) ----
  k_sq<<<NN/4, 256, 0, stream>>>(h3, sqv);
  k_split<<<NN, 256, 0, stream>>>(h3, xcat);
  k_gramtopk<<<dim3(SPL, NN/GT_RPB), 256, 0, stream>>>(xcat, sqv, pd, pi);
  k_knn_merge<<<NN/4, 256, 0, stream>>>(pd, pi, idx);
  k_wd<<<64, 256, 0, stream>>>(W21, Wd, 256, 64);
  k_mm<<<dim3(1, NN/64), 256, 0, stream>>>(h3, Wd, b21, Abuf, NN, 256, 64, 0);
  k_mm<<<dim3(1, NN/64), 256, 0, stream>>>(h3, W21 + 256*64, nullptr, Pbuf, NN, 256, 64, 0);
  k_zero<<<2, 256, 0, stream>>>(ssum, 256); k_zero<<<2, 256, 0, stream>>>(ssq, 256);
  k_stats1<64><<<NN*KNN/128, 256, 0, stream>>>(Abuf, Pbuf, idx, ssum, ssq);
  k_bn_final<<<1, 256, 0, stream>>>(ssum, ssq, g21, be21, sbn, tbn, 64, invn);
  k_edge_mm<64><<<NN*KNN/64, 256, 0, stream>>>(Abuf, Pbuf, idx, sbn, tbn, W22, b22, out2);
  k_zero<<<2, 256, 0, stream>>>(ssum, 256); k_zero<<<2, 256, 0, stream>>>(ssq, 256);
  k_colstats<64><<<NN*KNN/256, 256, 0, stream>>>(out2, ssum, ssq);
  k_bn_final<<<1, 256, 0, stream>>>(ssum, ssq, g22, be22, sbn, tbn, 64, invn);
  k_maxpool<64><<<NN/4, 256, 0, stream>>>(out2, sbn, tbn, h4);

  // gconv3 -> out
  k_agg<64><<<NN, 64, 0, stream>>>(h4, roff, csr, dout, din, xa);
  k_mm<<<dim3(1, NN/64), 256, 0, stream>>>(xa, Wc3, bc3, out, NN, 64, 32, 0);
}